// Round 14
// baseline (286.133 us; speedup 1.0000x reference)
//
#include <hip/hip_runtime.h>

#define HIDDEN 2048
#define S_LEN  2048
#define NH     32
#define NKV    8
#define HD     128
#define QKVN   6144   // 4096 q + 1024 k + 1024 v
#define OD     4096   // NH*HD

typedef float  f32x4   __attribute__((ext_vector_type(4)));
typedef float  f32x16  __attribute__((ext_vector_type(16)));
typedef __bf16 bf16x8  __attribute__((ext_vector_type(8)));
typedef __bf16 bf16x4  __attribute__((ext_vector_type(4)));
typedef unsigned int u32;

static __device__ __forceinline__ f32x4 mfma16(bf16x8 a, bf16x8 b, f32x4 c) {
  return __builtin_amdgcn_mfma_f32_16x16x32_bf16(a, b, c, 0, 0, 0);
}
static __device__ __forceinline__ f32x16 mfma32(bf16x8 a, bf16x8 b, f32x16 c) {
  return __builtin_amdgcn_mfma_f32_32x32x16_bf16(a, b, c, 0, 0, 0);
}
static __device__ __forceinline__ void gload_lds16(const void* g, void* l) {
  __builtin_amdgcn_global_load_lds(
      (__attribute__((address_space(1))) void*)(g),
      (__attribute__((address_space(3))) void*)(l), 16, 0, 0);
}
static __device__ __forceinline__ u32 pk_bf16(float lo, float hi) {
  u32 r;
  asm("v_cvt_pk_bf16_f32 %0, %1, %2" : "=v"(r) : "v"(lo), "v"(hi));
  return r;
}

// ---------- fp32 -> bf16 elementwise ----------
__global__ __launch_bounds__(256) void k_cvt(const float* __restrict__ in,
                                             __bf16* __restrict__ out, int n) {
  int i = (blockIdx.x * 256 + threadIdx.x) * 4;
  if (i >= n) return;
  float4 v = *reinterpret_cast<const float4*>(in + i);
  bf16x4 o = {(__bf16)v.x, (__bf16)v.y, (__bf16)v.z, (__bf16)v.w};
  *reinterpret_cast<bf16x4*>(out + i) = o;
}

// ---------- transpose + convert: src (K x N) f32 -> dst (N x K) bf16 ----------
__global__ __launch_bounds__(256) void k_transpose_cvt(const float* __restrict__ src,
                                                       __bf16* __restrict__ dst,
                                                       int K, int N) {
  __shared__ float tile[32][33];
  int tx = threadIdx.x & 31, ty = threadIdx.x >> 5;
  int n0 = blockIdx.x * 32, k0 = blockIdx.y * 32;
#pragma unroll
  for (int r = 0; r < 4; r++) {
    int k = ty + r * 8;
    tile[k][tx] = src[(size_t)(k0 + k) * N + n0 + tx];
  }
  __syncthreads();
#pragma unroll
  for (int r = 0; r < 4; r++) {
    int n = ty + r * 8;
    dst[(size_t)(n0 + n) * K + k0 + tx] = (__bf16)tile[tx][n];
  }
}

__global__ void k_bias_concat(const float* __restrict__ bq, const float* __restrict__ bk,
                              const float* __restrict__ bv, float* __restrict__ out) {
  int i = blockIdx.x * 256 + threadIdx.x;
  if (i >= QKVN) return;
  out[i] = (i < 4096) ? bq[i] : (i < 5120 ? bk[i - 4096] : bv[i - 5120]);
}

// ---------- V transpose: qkv (S x QKVN) v-cols -> vt (NKV x HD x S) ----------
__global__ __launch_bounds__(256) void k_vtrans(const __bf16* __restrict__ qkv,
                                                __bf16* __restrict__ vt) {
  __shared__ __bf16 tile[32][33];
  int tx = threadIdx.x & 31, ty = threadIdx.x >> 5;
  int s0 = blockIdx.x * 32, d0 = blockIdx.y * 32, kv = blockIdx.z;
#pragma unroll
  for (int r = 0; r < 4; r++) {
    int s = ty + r * 8;
    tile[s][tx] = qkv[(size_t)(s0 + s) * QKVN + 5120 + kv * HD + d0 + tx];
  }
  __syncthreads();
#pragma unroll
  for (int r = 0; r < 4; r++) {
    int d = ty + r * 8;
    vt[(size_t)(kv * HD + d0 + d) * S_LEN + s0 + tx] = tile[tx][d];
  }
}

// ---------- 256x256 BK=64 GEMM, 2 phases/K-tile (T2+T4+T5): C = (A@BT^T+bias)*colscale ----
// 512 threads = 8 waves (2M x 4N); per-wave C = 128x64 (8x4 frags 16x16x32).
// LDS 128 KiB: {A,B}[2 dbuf][2 K-half][256 rows][32 k] bf16, XOR swizzle
// slot^=((row>>1)&3), linear gload_lds dest + pre-swizzled source (rule #21).
// Phase = one K-half: {12 ds_reads + 4 prefetch gloads} -> barrier -> lgkmcnt(0)
// -> 32 MFMA -> counted-vmcnt publish -> barrier (publish waits BEFORE barrier
// so it covers ALL waves' staging loads). Counted vmcnt(4), never 0 mid-loop.
__global__ __launch_bounds__(512, 2) void k_gemm8(const __bf16* __restrict__ A,
                                                  const __bf16* __restrict__ BT,
                                                  const float* __restrict__ bias,
                                                  __bf16* __restrict__ C,
                                                  int M, int N, int K,
                                                  float oscale, int scale_cols) {
  __shared__ __bf16 Al[2][2][8192];
  __shared__ __bf16 Bl[2][2][8192];
  const int tid = threadIdx.x, lane = tid & 63, w = tid >> 6;
  const int l15 = lane & 15, lhi = lane >> 4;
  const int wr = w >> 2, wc = w & 3;
  const int mt = blockIdx.x & 7, nt = blockIdx.x >> 3;  // XCD-major: m-tile per XCD
  const int m0 = mt * 256, n0 = nt * 256;
  const int NKT = K >> 6;
  const __bf16* Ab = A + (size_t)m0 * K;
  const __bf16* Bb = BT + (size_t)n0 * K;

  f32x4 acc[8][4];
#pragma unroll
  for (int i = 0; i < 8; i++)
#pragma unroll
    for (int j = 0; j < 4; j++)
#pragma unroll
      for (int e = 0; e < 4; e++) acc[i][j][e] = 0.f;

// stage one K-half of one operand: 2 gload_lds per thread (16 KiB total)
#define SGH(dstA, srcB, buf, kh, ktile)                                           \
  do {                                                                            \
    _Pragma("unroll") for (int it = 0; it < 2; ++it) {                            \
      int c = it * 512 + tid;                                                     \
      int row = c >> 2, slot = c & 3;                                             \
      int scol = ((slot * 16) ^ (((row >> 1) & 3) << 4)) >> 1;                    \
      gload_lds16(srcB + (size_t)row * K + (ktile) * 64 + (kh) * 32 + scol,       \
                  &dstA[buf][kh][c * 8]);                                         \
    }                                                                             \
  } while (0)

#define RD_A(cb, kk)                                                              \
  do {                                                                            \
    _Pragma("unroll") for (int i = 0; i < 8; ++i) {                               \
      int row = wr * 128 + i * 16 + l15;                                          \
      af[i] = *(const bf16x8*)(&Al[cb][kk][row * 32 +                             \
                (((lhi * 16) ^ (((row >> 1) & 3) << 4)) >> 1)]);                  \
    }                                                                             \
  } while (0)

#define RD_B4(cb, kk)                                                             \
  do {                                                                            \
    _Pragma("unroll") for (int j = 0; j < 4; ++j) {                               \
      int row = wc * 64 + j * 16 + l15;                                           \
      bfr[j] = *(const bf16x8*)(&Bl[cb][kk][row * 32 +                            \
                (((lhi * 16) ^ (((row >> 1) & 3) << 4)) >> 1)]);                  \
    }                                                                             \
  } while (0)

#define MFMA32X                                                                   \
  do {                                                                            \
    __builtin_amdgcn_s_setprio(1);                                                \
    _Pragma("unroll") for (int i = 0; i < 8; ++i) {                               \
      _Pragma("unroll") for (int j = 0; j < 4; ++j) {                             \
        acc[i][j] = mfma16(af[i], bfr[j], acc[i][j]);                             \
      }                                                                           \
    }                                                                             \
    __builtin_amdgcn_s_setprio(0);                                                \
  } while (0)

  // prologue: all 4 half-pairs of K-tile 0 (oldest-first: K0 pair, then K1 pair)
  SGH(Al, Ab, 0, 0, 0);
  SGH(Bl, Bb, 0, 0, 0);
  SGH(Al, Ab, 0, 1, 0);
  SGH(Bl, Bb, 0, 1, 0);
  // PUBLISH K0(0): every wave waits its counted loads, THEN the barrier
  asm volatile("s_waitcnt vmcnt(4)" ::: "memory");
  __builtin_amdgcn_s_barrier();
  __builtin_amdgcn_sched_barrier(0);

  for (int kt = 0; kt < NKT; ++kt) {
    const int cb = kt & 1, pb = cb ^ 1;
    const bool pf = (kt + 1 < NKT);
    bf16x8 af[8], bfr[4];

    // ---- Phase A: K-half 0 (published) ----
    RD_A(cb, 0);
    RD_B4(cb, 0);
    if (pf) { SGH(Al, Ab, pb, 0, kt + 1); SGH(Bl, Bb, pb, 0, kt + 1); }
    __builtin_amdgcn_s_barrier();
    asm volatile("s_waitcnt lgkmcnt(0)" ::: "memory");
    MFMA32X;
    if (pf) {
      asm volatile("s_waitcnt vmcnt(4)" ::: "memory");  // K1(cb) landed; K0(next) in flight
    } else {
      asm volatile("s_waitcnt vmcnt(0)" ::: "memory");  // drain K1(last)
    }
    __builtin_amdgcn_s_barrier();   // PUBLISH K1(cb)
    __builtin_amdgcn_sched_barrier(0);

    // ---- Phase B: K-half 1 ----
    RD_A(cb, 1);
    RD_B4(cb, 1);
    if (pf) { SGH(Al, Ab, pb, 1, kt + 1); SGH(Bl, Bb, pb, 1, kt + 1); }
    __builtin_amdgcn_s_barrier();
    asm volatile("s_waitcnt lgkmcnt(0)" ::: "memory");
    MFMA32X;
    if (pf) {
      asm volatile("s_waitcnt vmcnt(4)" ::: "memory");  // K0(next) landed; K1(next) in flight
    }
    __builtin_amdgcn_s_barrier();   // PUBLISH K0(next)
    __builtin_amdgcn_sched_barrier(0);
  }
#undef SGH
#undef RD_A
#undef RD_B4
#undef MFMA32X

  // epilogue
#pragma unroll
  for (int j = 0; j < 4; j++) {
    int col = n0 + wc * 64 + j * 16 + l15;
    float bv = bias[col];
    float sc = (col < scale_cols) ? oscale : 1.0f;
#pragma unroll
    for (int i = 0; i < 8; i++) {
      int r0 = m0 + wr * 128 + i * 16 + lhi * 4;
#pragma unroll
      for (int rr = 0; rr < 4; rr++) {
        C[(size_t)(r0 + rr) * N + col] = (__bf16)((acc[i][j][rr] + bv) * sc);
      }
    }
  }
}

// ---------- split-K GEMM partial: Cpart[z] (MxN f32) = A @ BT^T over K-chunk z ----------
__global__ __launch_bounds__(256) void k_gemm_part(const __bf16* __restrict__ A,
                                                   const __bf16* __restrict__ BT,
                                                   float* __restrict__ Cpart,
                                                   int M, int N, int K, int KC) {
  __shared__ __bf16 Al[128 * 64];
  __shared__ __bf16 Bl[128 * 64];
  const int tid = threadIdx.x;
  const int lane = tid & 63;
  const int w = tid >> 6;
  const int m0 = blockIdx.y * 128;
  const int n0 = blockIdx.x * 128;
  const int kbeg = blockIdx.z * KC;
  const int wm = (w >> 1) * 64;
  const int wn = (w & 1) * 64;
  const int l15 = lane & 15, lhi = lane >> 4;

  f32x4 acc[4][4];
#pragma unroll
  for (int i = 0; i < 4; i++)
#pragma unroll
    for (int j = 0; j < 4; j++)
#pragma unroll
      for (int e = 0; e < 4; e++) acc[i][j][e] = 0.f;

  for (int kt = kbeg; kt < kbeg + KC; kt += 64) {
#pragma unroll
    for (int it = 0; it < 4; it++) {
      int idx = it * 256 + tid;
      int row = idx >> 3, slot = idx & 7;
      int scol = ((slot * 16) ^ ((row & 7) << 4)) >> 1;
      gload_lds16(A + (size_t)(m0 + row) * K + kt + scol, &Al[idx * 8]);
      gload_lds16(BT + (size_t)(n0 + row) * K + kt + scol, &Bl[idx * 8]);
    }
    __syncthreads();
#pragma unroll
    for (int kk = 0; kk < 2; kk++) {
      bf16x8 af[4], bfr[4];
#pragma unroll
      for (int i = 0; i < 4; i++) {
        int ra = wm + i * 16 + l15;
        int ba = (kk * 64 + lhi * 16) ^ ((ra & 7) << 4);
        af[i] = *(const bf16x8*)((const char*)Al + ra * 128 + ba);
        int rb = wn + i * 16 + l15;
        int bb = (kk * 64 + lhi * 16) ^ ((rb & 7) << 4);
        bfr[i] = *(const bf16x8*)((const char*)Bl + rb * 128 + bb);
      }
#pragma unroll
      for (int i = 0; i < 4; i++)
#pragma unroll
        for (int j = 0; j < 4; j++) acc[i][j] = mfma16(af[i], bfr[j], acc[i][j]);
    }
    __syncthreads();
  }
  float* C = Cpart + (size_t)blockIdx.z * M * N;
#pragma unroll
  for (int j = 0; j < 4; j++) {
    int col = n0 + wn + j * 16 + l15;
#pragma unroll
    for (int i = 0; i < 4; i++) {
      int r0 = m0 + wm + i * 16 + lhi * 4;
#pragma unroll
      for (int rr = 0; rr < 4; rr++) {
        C[(size_t)(r0 + rr) * N + col] = acc[i][j][rr];
      }
    }
  }
}

// ---------- combine split-K partials + bias -> f32 out ----------
__global__ __launch_bounds__(256) void k_ocombine(const float* __restrict__ a,
                                                  const float* __restrict__ b,
                                                  const float* __restrict__ bias,
                                                  float* __restrict__ out) {
  int i = (blockIdx.x * 256 + threadIdx.x) * 4;
  f32x4 va = *(const f32x4*)(a + i);
  f32x4 vb = *(const f32x4*)(b + i);
  f32x4 vbias = *(const f32x4*)(bias + (i & (HIDDEN - 1)));
  f32x4 r = va + vb + vbias;
  *(f32x4*)(out + i) = r;
}

// ---------- causal GQA flash attention (r12 decomposition, single-buffered K/V) ----------
// 512 blocks, 256 threads; ids i and i+256 get tiles t and 15-t. 4 waves x 32
// q-rows. SINGLE-buffered K/V (32 KiB LDS) -> 4 blocks/CU = 4 waves/SIMD: wave-
// level TLP replaces the double-buffer's pipelining (m114), doubling the
// latency-hiding pool for the serial QK->softmax->PV chain.
// S^T = mfma(K,Q) so q = lane&31 (softmax lane-local); P in registers via
// cvt_pk + permlane32_swap; O^T = mfma(V^T, P). LDS swizzles per rule #21:
//   Kl[key][d]: byte = key*256 + ((2d) ^ ((key&15)<<4))   (2-way, free)
//   Vl[d][k]:   byte = d*128  + ((2k) ^ ((d&7)<<4))       (4-way, 1.58x)
__global__ __launch_bounds__(256, 4) void k_attn(const __bf16* __restrict__ qkv,
                                                 const __bf16* __restrict__ vt,
                                                 __bf16* __restrict__ o) {
  __shared__ __bf16 Kl[8192];
  __shared__ __bf16 Vl[8192];
  const int tid = threadIdx.x, lane = tid & 63, w = tid >> 6;
  const int l31 = lane & 31, h = lane >> 5;

  // block-id pairing: ids i and i+256 get tiles t and 15-t (uniform CU load)
  const int id = blockIdx.x;
  int tile, head;
  if (id < 256) { head = id >> 4; tile = id & 15; }
  else          { head = 16 + ((id - 256) >> 4); tile = 15 - (id & 15); }
  const int kvh = head >> 2;
  const int qbase = tile * 128 + w * 32;
  const int qg = qbase + l31;          // this lane's q row
  const int kdiag = (qbase + 31) >> 6; // last (partial) key tile for this wave
  const int nkt = 2 * tile + 2;

  // Q fragments (pre-scaled by 1/sqrt(d) in QKV GEMM epilogue): B-frag col=q
  bf16x8 qf[8];
  {
    const __bf16* qrow = qkv + (size_t)qg * QKVN + head * HD;
#pragma unroll
    for (int dk = 0; dk < 8; dk++) qf[dk] = *(const bf16x8*)(qrow + dk * 16 + h * 8);
  }

  f32x16 acc[4];  // O^T: col=q=lane&31, row=d (reg-mapped), dt*32 block
#pragma unroll
  for (int dt = 0; dt < 4; dt++)
#pragma unroll
    for (int r = 0; r < 16; r++) acc[dt][r] = 0.f;
  float m = -INFINITY, lsum = 0.f;

#define STAGE(ktile)                                                                \
  do {                                                                              \
    const int kk0 = (ktile) * 64;                                                   \
    _Pragma("unroll") for (int it = 0; it < 4; it++) {                              \
      int c = it * 256 + tid;                                                       \
      int key = c >> 4, slot = c & 15;                                              \
      int scol = ((slot * 16) ^ ((key & 15) << 4)) >> 1;                            \
      gload_lds16(qkv + (size_t)(kk0 + key) * QKVN + 4096 + kvh * HD + scol,        \
                  &Kl[c * 8]);                                                      \
    }                                                                               \
    _Pragma("unroll") for (int it = 0; it < 4; it++) {                              \
      int c = it * 256 + tid;                                                       \
      int d = c >> 3, slot = c & 7;                                                 \
      int scol = ((slot * 16) ^ ((d & 7) << 4)) >> 1;                               \
      gload_lds16(vt + (size_t)(kvh * HD + d) * S_LEN + kk0 + scol,                 \
                  &Vl[c * 8]);                                                      \
    }                                                                               \
  } while (0)

  for (int kt = 0; kt < nkt; kt++) {
    STAGE(kt);
    __syncthreads();   // compiler drains vmcnt(0) before barrier: tile published

    if (kt <= kdiag) {
      const char* Kb = (const char*)&Kl[0];
      const char* Vb = (const char*)&Vl[0];
      const int k0 = kt * 64;
      // ---- QK^T: S^T[key][q], two 32-key blocks ----
      f32x16 sacc[2];
#pragma unroll
      for (int b = 0; b < 2; b++)
#pragma unroll
        for (int r = 0; r < 16; r++) sacc[b][r] = 0.f;
      __builtin_amdgcn_s_setprio(1);
#pragma unroll
      for (int dk = 0; dk < 8; dk++) {
        const int sA = ((2 * dk + h) ^ (l31 & 15)) * 16;
        bf16x8 kf0 = *(const bf16x8*)(Kb + l31 * 256 + sA);
        bf16x8 kf1 = *(const bf16x8*)(Kb + (32 + l31) * 256 + sA);
        sacc[0] = mfma32(kf0, qf[dk], sacc[0]);
        sacc[1] = mfma32(kf1, qf[dk], sacc[1]);
      }
      __builtin_amdgcn_s_setprio(0);
      // ---- softmax (lane-local; q = lane&31) ----
      float p[32];
#pragma unroll
      for (int b = 0; b < 2; b++)
#pragma unroll
        for (int r = 0; r < 16; r++) p[b * 16 + r] = sacc[b][r];
      if (kt == kdiag) {  // mask only on the diagonal tile
#pragma unroll
        for (int b = 0; b < 2; b++)
#pragma unroll
          for (int r = 0; r < 16; r++) {
            int keyg = k0 + b * 32 + (r & 3) + 8 * (r >> 2) + 4 * h;
            if (keyg > qg) p[b * 16 + r] = -INFINITY;
          }
      }
      // pairwise max tree (depth 5)
      float t16[16], t8[8], t4[4];
#pragma unroll
      for (int i = 0; i < 16; i++) t16[i] = fmaxf(p[2 * i], p[2 * i + 1]);
#pragma unroll
      for (int i = 0; i < 8; i++) t8[i] = fmaxf(t16[2 * i], t16[2 * i + 1]);
#pragma unroll
      for (int i = 0; i < 4; i++) t4[i] = fmaxf(t8[2 * i], t8[2 * i + 1]);
      float pm = fmaxf(fmaxf(t4[0], t4[1]), fmaxf(t4[2], t4[3]));
      pm = fmaxf(pm, __shfl_xor(pm, 32));
      if (__any(pm - m > 8.f)) {  // defer-max (T13)
        float mn = fmaxf(m, pm);
        float corr = __expf(m - mn);
        m = mn;
        lsum *= corr;
#pragma unroll
        for (int dt = 0; dt < 4; dt++)
#pragma unroll
          for (int r = 0; r < 16; r++) acc[dt][r] *= corr;
      }
      float psum = 0.f;
#pragma unroll
      for (int i = 0; i < 32; i++) { p[i] = __expf(p[i] - m); psum += p[i]; }
      lsum += psum;
      // ---- PV: O^T += V^T * P, P-frags built in-register ----
      // permlane32_swap(W0,W2): W0 -> {lo:W0@h0, hi:W2@h0}, W2 -> {lo:W0@h1, hi:W2@h1}.
#pragma unroll
      for (int ks2 = 0; ks2 < 4; ks2++) {
        const int o8 = (ks2 >> 1) * 16 + (ks2 & 1) * 8;
        u32 W0 = pk_bf16(p[o8 + 0], p[o8 + 1]);
        u32 W1 = pk_bf16(p[o8 + 2], p[o8 + 3]);
        u32 W2 = pk_bf16(p[o8 + 4], p[o8 + 5]);
        u32 W3 = pk_bf16(p[o8 + 6], p[o8 + 7]);
        asm("v_permlane32_swap_b32 %0, %1" : "+v"(W0), "+v"(W2));
        asm("v_permlane32_swap_b32 %0, %1" : "+v"(W1), "+v"(W3));
        union { u32 wd[4]; bf16x8 v; } pu;
        pu.wd[0] = W0; pu.wd[1] = W1; pu.wd[2] = W2; pu.wd[3] = W3;
        __builtin_amdgcn_s_setprio(1);
#pragma unroll
        for (int dt = 0; dt < 4; dt++) {
          const int dr = dt * 32 + l31;
          const int sV = ((2 * ks2 + h) ^ (dr & 7)) * 16;
          bf16x8 vf = *(const bf16x8*)(Vb + dr * 128 + sV);
          acc[dt] = mfma32(vf, pu.v, acc[dt]);
        }
        __builtin_amdgcn_s_setprio(0);
      }
    }
    __syncthreads();  // all waves done reading before next STAGE overwrites
  }
#undef STAGE

  // ---- finalize: combine the two key-halves, normalize, store ----
  lsum += __shfl_xor(lsum, 32);
  const float inv = 1.f / lsum;
  __bf16* orow = o + (size_t)qg * OD + head * HD;
#pragma unroll
  for (int dt = 0; dt < 4; dt++)
#pragma unroll
    for (int rq = 0; rq < 4; rq++) {  // reg quads -> 4 consecutive d
      int d = dt * 32 + 8 * rq + 4 * h;
      bf16x4 ov = {(__bf16)(acc[dt][rq * 4 + 0] * inv), (__bf16)(acc[dt][rq * 4 + 1] * inv),
                   (__bf16)(acc[dt][rq * 4 + 2] * inv), (__bf16)(acc[dt][rq * 4 + 3] * inv)};
      *(bf16x4*)(orow + d) = ov;
    }
}

extern "C" void kernel_launch(void* const* d_in, const int* in_sizes, int n_in,
                              void* d_out, int out_size, void* d_ws, size_t ws_size,
                              hipStream_t stream) {
  const float* x  = (const float*)d_in[0];
  // d_in[1] = mask (tril causal; hard-coded in kernel)
  const float* wq = (const float*)d_in[2];
  const float* bq = (const float*)d_in[3];
  const float* wk = (const float*)d_in[4];
  const float* bk = (const float*)d_in[5];
  const float* wv = (const float*)d_in[6];
  const float* bv = (const float*)d_in[7];
  const float* wo = (const float*)d_in[8];
  const float* bo = (const float*)d_in[9];
  float* out = (float*)d_out;

  const size_t MB = 1024 * 1024;
  char* ws = (char*)d_ws;
  __bf16* xb    = (__bf16*)(ws);             //  8 MiB: 2048x2048 (dead after QKV GEMM)
  __bf16* wqkvT = (__bf16*)(ws + 8 * MB);    // 24 MiB (dead after QKV GEMM)
  __bf16* woT   = (__bf16*)(ws + 32 * MB);   // 16 MiB: 2048x4096
  __bf16* qkvb  = (__bf16*)(ws + 48 * MB);   // 24 MiB: 2048x6144
  __bf16* vtb   = (__bf16*)(ws + 72 * MB);   //  4 MiB: 8x128x2048
  __bf16* ob    = (__bf16*)(ws + 76 * MB);   // 16 MiB: 2048x4096
  float*  bqkv  = (float*)(ws + 92 * MB);    // 24 KiB
  float*  Cpart = (float*)(ws);              // 32 MiB: 2x(2048x2048 f32), reuses xb+wqkvT

  k_cvt<<<4096, 256, 0, stream>>>(x, xb, HIDDEN * S_LEN);
  k_transpose_cvt<<<dim3(128, 64), 256, 0, stream>>>(wq, wqkvT, HIDDEN, 4096);
  k_transpose_cvt<<<dim3(32, 64), 256, 0, stream>>>(wk, wqkvT + (size_t)4096 * HIDDEN, HIDDEN, 1024);
  k_transpose_cvt<<<dim3(32, 64), 256, 0, stream>>>(wv, wqkvT + (size_t)5120 * HIDDEN, HIDDEN, 1024);
  k_transpose_cvt<<<dim3(64, 128), 256, 0, stream>>>(wo, woT, 4096, HIDDEN);
  k_bias_concat<<<24, 256, 0, stream>>>(bq, bk, bv, bqkv);

  // QKV projection: 256^2 2-phase/K-tile GEMM (192 blocks, XCD-major m), Q pre-scaled
  k_gemm8<<<192, 512, 0, stream>>>(xb, wqkvT, bqkv, qkvb, S_LEN, QKVN, HIDDEN,
                                   0.08838834764831845f, 4096);
  k_vtrans<<<dim3(S_LEN / 32, HD / 32, NKV), 256, 0, stream>>>(qkvb, vtb);
  k_attn<<<512, 256, 0, stream>>>(qkvb, vtb, ob);
  // O-projection: split-K=2 (512 blocks -> 2 blocks/CU) + combine with bias
  k_gemm_part<<<dim3(HIDDEN / 128, S_LEN / 128, 2), 256, 0, stream>>>(
      ob, woT, Cpart, S_LEN, HIDDEN, OD, OD / 2);
  k_ocombine<<<(S_LEN * HIDDEN) / 1024, 256, 0, stream>>>(
      Cpart, Cpart + (size_t)S_LEN * HIDDEN, bo, out);
}

// Round 15
// 235.898 us; speedup vs baseline: 1.2130x; 1.2130x over previous
//
#include <hip/hip_runtime.h>

#define HIDDEN 2048
#define S_LEN  2048
#define NH     32
#define NKV    8
#define HD     128
#define QKVN   6144   // 4096 q + 1024 k + 1024 v
#define OD     4096   // NH*HD

typedef float  f32x4   __attribute__((ext_vector_type(4)));
typedef float  f32x16  __attribute__((ext_vector_type(16)));
typedef __bf16 bf16x8  __attribute__((ext_vector_type(8)));
typedef __bf16 bf16x4  __attribute__((ext_vector_type(4)));
typedef unsigned int u32;

static __device__ __forceinline__ f32x4 mfma16(bf16x8 a, bf16x8 b, f32x4 c) {
  return __builtin_amdgcn_mfma_f32_16x16x32_bf16(a, b, c, 0, 0, 0);
}
static __device__ __forceinline__ f32x16 mfma32(bf16x8 a, bf16x8 b, f32x16 c) {
  return __builtin_amdgcn_mfma_f32_32x32x16_bf16(a, b, c, 0, 0, 0);
}
static __device__ __forceinline__ void gload_lds16(const void* g, void* l) {
  __builtin_amdgcn_global_load_lds(
      (__attribute__((address_space(1))) void*)(g),
      (__attribute__((address_space(3))) void*)(l), 16, 0, 0);
}
static __device__ __forceinline__ u32 pk_bf16(float lo, float hi) {
  u32 r;
  asm("v_cvt_pk_bf16_f32 %0, %1, %2" : "=v"(r) : "v"(lo), "v"(hi));
  return r;
}

// ---------- fp32 -> bf16 elementwise ----------
__global__ __launch_bounds__(256) void k_cvt(const float* __restrict__ in,
                                             __bf16* __restrict__ out, int n) {
  int i = (blockIdx.x * 256 + threadIdx.x) * 4;
  if (i >= n) return;
  float4 v = *reinterpret_cast<const float4*>(in + i);
  bf16x4 o = {(__bf16)v.x, (__bf16)v.y, (__bf16)v.z, (__bf16)v.w};
  *reinterpret_cast<bf16x4*>(out + i) = o;
}

// ---------- transpose + convert: src (K x N) f32 -> dst (N x K) bf16 ----------
__global__ __launch_bounds__(256) void k_transpose_cvt(const float* __restrict__ src,
                                                       __bf16* __restrict__ dst,
                                                       int K, int N) {
  __shared__ float tile[32][33];
  int tx = threadIdx.x & 31, ty = threadIdx.x >> 5;
  int n0 = blockIdx.x * 32, k0 = blockIdx.y * 32;
#pragma unroll
  for (int r = 0; r < 4; r++) {
    int k = ty + r * 8;
    tile[k][tx] = src[(size_t)(k0 + k) * N + n0 + tx];
  }
  __syncthreads();
#pragma unroll
  for (int r = 0; r < 4; r++) {
    int n = ty + r * 8;
    dst[(size_t)(n0 + n) * K + k0 + tx] = (__bf16)tile[tx][n];
  }
}

__global__ void k_bias_concat(const float* __restrict__ bq, const float* __restrict__ bk,
                              const float* __restrict__ bv, float* __restrict__ out) {
  int i = blockIdx.x * 256 + threadIdx.x;
  if (i >= QKVN) return;
  out[i] = (i < 4096) ? bq[i] : (i < 5120 ? bk[i - 4096] : bv[i - 5120]);
}

// ---------- V transpose: qkv (S x QKVN) v-cols -> vt (NKV x HD x S) ----------
__global__ __launch_bounds__(256) void k_vtrans(const __bf16* __restrict__ qkv,
                                                __bf16* __restrict__ vt) {
  __shared__ __bf16 tile[32][33];
  int tx = threadIdx.x & 31, ty = threadIdx.x >> 5;
  int s0 = blockIdx.x * 32, d0 = blockIdx.y * 32, kv = blockIdx.z;
#pragma unroll
  for (int r = 0; r < 4; r++) {
    int s = ty + r * 8;
    tile[s][tx] = qkv[(size_t)(s0 + s) * QKVN + 5120 + kv * HD + d0 + tx];
  }
  __syncthreads();
#pragma unroll
  for (int r = 0; r < 4; r++) {
    int d = ty + r * 8;
    vt[(size_t)(kv * HD + d0 + d) * S_LEN + s0 + tx] = tile[tx][d];
  }
}

// ---------- 256x256 BK=64 GEMM, 2 phases/K-tile (T2+T4+T5): C = (A@BT^T+bias)*colscale ----
// 512 threads = 8 waves (2M x 4N); per-wave C = 128x64 (8x4 frags 16x16x32).
// LDS 128 KiB: {A,B}[2 dbuf][2 K-half][256 rows][32 k] bf16, XOR swizzle
// slot^=((row>>1)&3), linear gload_lds dest + pre-swizzled source (rule #21).
// Phase = one K-half: {12 ds_reads + 4 prefetch gloads} -> barrier -> lgkmcnt(0)
// -> 32 MFMA -> counted-vmcnt publish -> barrier (publish waits BEFORE barrier
// so it covers ALL waves' staging loads). Counted vmcnt(4), never 0 mid-loop.
__global__ __launch_bounds__(512, 2) void k_gemm8(const __bf16* __restrict__ A,
                                                  const __bf16* __restrict__ BT,
                                                  const float* __restrict__ bias,
                                                  __bf16* __restrict__ C,
                                                  int M, int N, int K,
                                                  float oscale, int scale_cols) {
  __shared__ __bf16 Al[2][2][8192];
  __shared__ __bf16 Bl[2][2][8192];
  const int tid = threadIdx.x, lane = tid & 63, w = tid >> 6;
  const int l15 = lane & 15, lhi = lane >> 4;
  const int wr = w >> 2, wc = w & 3;
  const int mt = blockIdx.x & 7, nt = blockIdx.x >> 3;  // XCD-major: m-tile per XCD
  const int m0 = mt * 256, n0 = nt * 256;
  const int NKT = K >> 6;
  const __bf16* Ab = A + (size_t)m0 * K;
  const __bf16* Bb = BT + (size_t)n0 * K;

  f32x4 acc[8][4];
#pragma unroll
  for (int i = 0; i < 8; i++)
#pragma unroll
    for (int j = 0; j < 4; j++)
#pragma unroll
      for (int e = 0; e < 4; e++) acc[i][j][e] = 0.f;

// stage one K-half of one operand: 2 gload_lds per thread (16 KiB total)
#define SGH(dstA, srcB, buf, kh, ktile)                                           \
  do {                                                                            \
    _Pragma("unroll") for (int it = 0; it < 2; ++it) {                            \
      int c = it * 512 + tid;                                                     \
      int row = c >> 2, slot = c & 3;                                             \
      int scol = ((slot * 16) ^ (((row >> 1) & 3) << 4)) >> 1;                    \
      gload_lds16(srcB + (size_t)row * K + (ktile) * 64 + (kh) * 32 + scol,       \
                  &dstA[buf][kh][c * 8]);                                         \
    }                                                                             \
  } while (0)

#define RD_A(cb, kk)                                                              \
  do {                                                                            \
    _Pragma("unroll") for (int i = 0; i < 8; ++i) {                               \
      int row = wr * 128 + i * 16 + l15;                                          \
      af[i] = *(const bf16x8*)(&Al[cb][kk][row * 32 +                             \
                (((lhi * 16) ^ (((row >> 1) & 3) << 4)) >> 1)]);                  \
    }                                                                             \
  } while (0)

#define RD_B4(cb, kk)                                                             \
  do {                                                                            \
    _Pragma("unroll") for (int j = 0; j < 4; ++j) {                               \
      int row = wc * 64 + j * 16 + l15;                                           \
      bfr[j] = *(const bf16x8*)(&Bl[cb][kk][row * 32 +                            \
                (((lhi * 16) ^ (((row >> 1) & 3) << 4)) >> 1)]);                  \
    }                                                                             \
  } while (0)

#define MFMA32X                                                                   \
  do {                                                                            \
    __builtin_amdgcn_s_setprio(1);                                                \
    _Pragma("unroll") for (int i = 0; i < 8; ++i) {                               \
      _Pragma("unroll") for (int j = 0; j < 4; ++j) {                             \
        acc[i][j] = mfma16(af[i], bfr[j], acc[i][j]);                             \
      }                                                                           \
    }                                                                             \
    __builtin_amdgcn_s_setprio(0);                                                \
  } while (0)

  // prologue: all 4 half-pairs of K-tile 0 (oldest-first: K0 pair, then K1 pair)
  SGH(Al, Ab, 0, 0, 0);
  SGH(Bl, Bb, 0, 0, 0);
  SGH(Al, Ab, 0, 1, 0);
  SGH(Bl, Bb, 0, 1, 0);
  // PUBLISH K0(0): every wave waits its counted loads, THEN the barrier
  asm volatile("s_waitcnt vmcnt(4)" ::: "memory");
  __builtin_amdgcn_s_barrier();
  __builtin_amdgcn_sched_barrier(0);

  for (int kt = 0; kt < NKT; ++kt) {
    const int cb = kt & 1, pb = cb ^ 1;
    const bool pf = (kt + 1 < NKT);
    bf16x8 af[8], bfr[4];

    // ---- Phase A: K-half 0 (published) ----
    RD_A(cb, 0);
    RD_B4(cb, 0);
    if (pf) { SGH(Al, Ab, pb, 0, kt + 1); SGH(Bl, Bb, pb, 0, kt + 1); }
    __builtin_amdgcn_s_barrier();
    asm volatile("s_waitcnt lgkmcnt(0)" ::: "memory");
    MFMA32X;
    if (pf) {
      asm volatile("s_waitcnt vmcnt(4)" ::: "memory");  // K1(cb) landed; K0(next) in flight
    } else {
      asm volatile("s_waitcnt vmcnt(0)" ::: "memory");  // drain K1(last)
    }
    __builtin_amdgcn_s_barrier();   // PUBLISH K1(cb)
    __builtin_amdgcn_sched_barrier(0);

    // ---- Phase B: K-half 1 ----
    RD_A(cb, 1);
    RD_B4(cb, 1);
    if (pf) { SGH(Al, Ab, pb, 1, kt + 1); SGH(Bl, Bb, pb, 1, kt + 1); }
    __builtin_amdgcn_s_barrier();
    asm volatile("s_waitcnt lgkmcnt(0)" ::: "memory");
    MFMA32X;
    if (pf) {
      asm volatile("s_waitcnt vmcnt(4)" ::: "memory");  // K0(next) landed; K1(next) in flight
    }
    __builtin_amdgcn_s_barrier();   // PUBLISH K0(next)
    __builtin_amdgcn_sched_barrier(0);
  }
#undef SGH
#undef RD_A
#undef RD_B4
#undef MFMA32X

  // epilogue
#pragma unroll
  for (int j = 0; j < 4; j++) {
    int col = n0 + wc * 64 + j * 16 + l15;
    float bv = bias[col];
    float sc = (col < scale_cols) ? oscale : 1.0f;
#pragma unroll
    for (int i = 0; i < 8; i++) {
      int r0 = m0 + wr * 128 + i * 16 + lhi * 4;
#pragma unroll
      for (int rr = 0; rr < 4; rr++) {
        C[(size_t)(r0 + rr) * N + col] = (__bf16)((acc[i][j][rr] + bv) * sc);
      }
    }
  }
}

// ---------- split-K GEMM partial: Cpart[z] (MxN f32) = A @ BT^T over K-chunk z ----------
__global__ __launch_bounds__(256) void k_gemm_part(const __bf16* __restrict__ A,
                                                   const __bf16* __restrict__ BT,
                                                   float* __restrict__ Cpart,
                                                   int M, int N, int K, int KC) {
  __shared__ __bf16 Al[128 * 64];
  __shared__ __bf16 Bl[128 * 64];
  const int tid = threadIdx.x;
  const int lane = tid & 63;
  const int w = tid >> 6;
  const int m0 = blockIdx.y * 128;
  const int n0 = blockIdx.x * 128;
  const int kbeg = blockIdx.z * KC;
  const int wm = (w >> 1) * 64;
  const int wn = (w & 1) * 64;
  const int l15 = lane & 15, lhi = lane >> 4;

  f32x4 acc[4][4];
#pragma unroll
  for (int i = 0; i < 4; i++)
#pragma unroll
    for (int j = 0; j < 4; j++)
#pragma unroll
      for (int e = 0; e < 4; e++) acc[i][j][e] = 0.f;

  for (int kt = kbeg; kt < kbeg + KC; kt += 64) {
#pragma unroll
    for (int it = 0; it < 4; it++) {
      int idx = it * 256 + tid;
      int row = idx >> 3, slot = idx & 7;
      int scol = ((slot * 16) ^ ((row & 7) << 4)) >> 1;
      gload_lds16(A + (size_t)(m0 + row) * K + kt + scol, &Al[idx * 8]);
      gload_lds16(BT + (size_t)(n0 + row) * K + kt + scol, &Bl[idx * 8]);
    }
    __syncthreads();
#pragma unroll
    for (int kk = 0; kk < 2; kk++) {
      bf16x8 af[4], bfr[4];
#pragma unroll
      for (int i = 0; i < 4; i++) {
        int ra = wm + i * 16 + l15;
        int ba = (kk * 64 + lhi * 16) ^ ((ra & 7) << 4);
        af[i] = *(const bf16x8*)((const char*)Al + ra * 128 + ba);
        int rb = wn + i * 16 + l15;
        int bb = (kk * 64 + lhi * 16) ^ ((rb & 7) << 4);
        bfr[i] = *(const bf16x8*)((const char*)Bl + rb * 128 + bb);
      }
#pragma unroll
      for (int i = 0; i < 4; i++)
#pragma unroll
        for (int j = 0; j < 4; j++) acc[i][j] = mfma16(af[i], bfr[j], acc[i][j]);
    }
    __syncthreads();
  }
  float* C = Cpart + (size_t)blockIdx.z * M * N;
#pragma unroll
  for (int j = 0; j < 4; j++) {
    int col = n0 + wn + j * 16 + l15;
#pragma unroll
    for (int i = 0; i < 4; i++) {
      int r0 = m0 + wm + i * 16 + lhi * 4;
#pragma unroll
      for (int rr = 0; rr < 4; rr++) {
        C[(size_t)(r0 + rr) * N + col] = acc[i][j][rr];
      }
    }
  }
}

// ---------- combine split-K partials + bias -> f32 out ----------
__global__ __launch_bounds__(256) void k_ocombine(const float* __restrict__ a,
                                                  const float* __restrict__ b,
                                                  const float* __restrict__ bias,
                                                  float* __restrict__ out) {
  int i = (blockIdx.x * 256 + threadIdx.x) * 4;
  f32x4 va = *(const f32x4*)(a + i);
  f32x4 vb = *(const f32x4*)(b + i);
  f32x4 vbias = *(const f32x4*)(bias + (i & (HIDDEN - 1)));
  f32x4 r = va + vb + vbias;
  *(f32x4*)(out + i) = r;
}

// ---------- causal GQA flash attention (same-tile pairing + coalesced staging) ----------
// 512 blocks, 256 threads, double-buffered K/V (64 KiB). SAME-TILE pairing:
// blocks c and c+256 (co-resident on a CU under round-robin dispatch) get the
// SAME q-tile (tile = id&15) and heads h, h+16 -> both resident blocks run the
// same duration, so the makespan CU (t=15) keeps 2-block concurrency for all
// 32 tiles (the r4 anti-pairing ran 30 of 32 tiles with ONE block = 1 wave/SIMD).
// S^T = mfma(K,Q) so q = lane&31 (softmax lane-local); P in registers via
// cvt_pk + permlane32_swap; O^T = mfma(V^T, P). LDS swizzles per rule #21:
//   Kl[key][d]: byte = key*256 + ((2d) ^ ((key&15)<<4))   (reads 2-way, free)
//   Vl[d][k]:   byte = d*128  + ((2k) ^ ((d&7)<<4))       (reads 4-way, 1.58x)
__global__ __launch_bounds__(256, 2) void k_attn(const __bf16* __restrict__ qkv,
                                                 const __bf16* __restrict__ vt,
                                                 __bf16* __restrict__ o) {
  __shared__ __bf16 Kl[2][8192];
  __shared__ __bf16 Vl[2][8192];
  const int tid = threadIdx.x, lane = tid & 63, w = tid >> 6;
  const int l31 = lane & 31, h = lane >> 5;

  // same-tile pairing: ids c, c+256 -> same tile, heads h, h+16
  const int id = blockIdx.x;
  const int head = id >> 4;            // 0..31
  const int tile = id & 15;            // same for c and c+256
  const int kvh = head >> 2;
  const int qbase = tile * 128 + w * 32;
  const int qg = qbase + l31;          // this lane's q row
  const int kdiag = (qbase + 31) >> 6; // last (partial) key tile for this wave
  const int nkt = 2 * tile + 2;

  // Q fragments (pre-scaled by 1/sqrt(d) in QKV GEMM epilogue): B-frag col=q
  bf16x8 qf[8];
  {
    const __bf16* qrow = qkv + (size_t)qg * QKVN + head * HD;
#pragma unroll
    for (int dk = 0; dk < 8; dk++) qf[dk] = *(const bf16x8*)(qrow + dk * 16 + h * 8);
  }

  f32x16 acc[4];  // O^T: col=q=lane&31, row=d (reg-mapped), dt*32 block
#pragma unroll
  for (int dt = 0; dt < 4; dt++)
#pragma unroll
    for (int r = 0; r < 16; r++) acc[dt][r] = 0.f;
  float m = -INFINITY, lsum = 0.f;

#define STAGE(buf, ktile)                                                           \
  do {                                                                              \
    const int kk0 = (ktile) * 64;                                                   \
    _Pragma("unroll") for (int it = 0; it < 4; it++) {                              \
      int c = it * 256 + tid;                                                       \
      int key = c >> 4, slot = c & 15;                                              \
      int scol = ((slot * 16) ^ ((key & 15) << 4)) >> 1;                            \
      gload_lds16(qkv + (size_t)(kk0 + key) * QKVN + 4096 + kvh * HD + scol,        \
                  &Kl[buf][c * 8]);                                                 \
    }                                                                               \
    _Pragma("unroll") for (int it = 0; it < 4; it++) {                              \
      int c = it * 256 + tid;                                                       \
      int d = c >> 3, slot = c & 7;                                                 \
      int scol = ((slot * 16) ^ ((d & 7) << 4)) >> 1;                               \
      gload_lds16(vt + (size_t)(kvh * HD + d) * S_LEN + kk0 + scol,                 \
                  &Vl[buf][c * 8]);                                                 \
    }                                                                               \
  } while (0)

  STAGE(0, 0);
  __syncthreads();

  for (int kt = 0; kt < nkt; kt++) {
    const int cur = kt & 1;
    if (kt + 1 < nkt) STAGE(cur ^ 1, kt + 1);  // in flight during compute

    if (kt <= kdiag) {
      const char* Kb = (const char*)&Kl[cur][0];
      const char* Vb = (const char*)&Vl[cur][0];
      const int k0 = kt * 64;
      // ---- QK^T: S^T[key][q], two 32-key blocks ----
      f32x16 sacc[2];
#pragma unroll
      for (int b = 0; b < 2; b++)
#pragma unroll
        for (int r = 0; r < 16; r++) sacc[b][r] = 0.f;
      __builtin_amdgcn_s_setprio(1);
#pragma unroll
      for (int dk = 0; dk < 8; dk++) {
        const int sA = ((2 * dk + h) ^ (l31 & 15)) * 16;
        bf16x8 kf0 = *(const bf16x8*)(Kb + l31 * 256 + sA);
        bf16x8 kf1 = *(const bf16x8*)(Kb + (32 + l31) * 256 + sA);
        sacc[0] = mfma32(kf0, qf[dk], sacc[0]);
        sacc[1] = mfma32(kf1, qf[dk], sacc[1]);
      }
      __builtin_amdgcn_s_setprio(0);
      // ---- softmax (lane-local; q = lane&31) ----
      float p[32];
#pragma unroll
      for (int b = 0; b < 2; b++)
#pragma unroll
        for (int r = 0; r < 16; r++) p[b * 16 + r] = sacc[b][r];
      if (kt == kdiag) {  // mask only on the diagonal tile
#pragma unroll
        for (int b = 0; b < 2; b++)
#pragma unroll
          for (int r = 0; r < 16; r++) {
            int keyg = k0 + b * 32 + (r & 3) + 8 * (r >> 2) + 4 * h;
            if (keyg > qg) p[b * 16 + r] = -INFINITY;
          }
      }
      // pairwise max tree (depth 5)
      float t16[16], t8[8], t4[4];
#pragma unroll
      for (int i = 0; i < 16; i++) t16[i] = fmaxf(p[2 * i], p[2 * i + 1]);
#pragma unroll
      for (int i = 0; i < 8; i++) t8[i] = fmaxf(t16[2 * i], t16[2 * i + 1]);
#pragma unroll
      for (int i = 0; i < 4; i++) t4[i] = fmaxf(t8[2 * i], t8[2 * i + 1]);
      float pm = fmaxf(fmaxf(t4[0], t4[1]), fmaxf(t4[2], t4[3]));
      pm = fmaxf(pm, __shfl_xor(pm, 32));
      if (__any(pm - m > 8.f)) {  // defer-max (T13)
        float mn = fmaxf(m, pm);
        float corr = __expf(m - mn);
        m = mn;
        lsum *= corr;
#pragma unroll
        for (int dt = 0; dt < 4; dt++)
#pragma unroll
          for (int r = 0; r < 16; r++) acc[dt][r] *= corr;
      }
      float psum = 0.f;
#pragma unroll
      for (int i = 0; i < 32; i++) { p[i] = __expf(p[i] - m); psum += p[i]; }
      lsum += psum;
      // ---- PV: O^T += V^T * P, P-frags built in-register ----
      // permlane32_swap(W0,W2): W0 -> {lo:W0@h0, hi:W2@h0}, W2 -> {lo:W0@h1, hi:W2@h1}.
#pragma unroll
      for (int ks2 = 0; ks2 < 4; ks2++) {
        const int o8 = (ks2 >> 1) * 16 + (ks2 & 1) * 8;
        u32 W0 = pk_bf16(p[o8 + 0], p[o8 + 1]);
        u32 W1 = pk_bf16(p[o8 + 2], p[o8 + 3]);
        u32 W2 = pk_bf16(p[o8 + 4], p[o8 + 5]);
        u32 W3 = pk_bf16(p[o8 + 6], p[o8 + 7]);
        asm("v_permlane32_swap_b32 %0, %1" : "+v"(W0), "+v"(W2));
        asm("v_permlane32_swap_b32 %0, %1" : "+v"(W1), "+v"(W3));
        union { u32 wd[4]; bf16x8 v; } pu;
        pu.wd[0] = W0; pu.wd[1] = W1; pu.wd[2] = W2; pu.wd[3] = W3;
        __builtin_amdgcn_s_setprio(1);
#pragma unroll
        for (int dt = 0; dt < 4; dt++) {
          const int dr = dt * 32 + l31;
          const int sV = ((2 * ks2 + h) ^ (dr & 7)) * 16;
          bf16x8 vf = *(const bf16x8*)(Vb + dr * 128 + sV);
          acc[dt] = mfma32(vf, pu.v, acc[dt]);
        }
        __builtin_amdgcn_s_setprio(0);
      }
    }
    __syncthreads();  // drains vmcnt: next tile landed; buffers safe to swap
  }
#undef STAGE

  // ---- finalize: combine the two key-halves, normalize, store ----
  lsum += __shfl_xor(lsum, 32);
  const float inv = 1.f / lsum;
  __bf16* orow = o + (size_t)qg * OD + head * HD;
#pragma unroll
  for (int dt = 0; dt < 4; dt++)
#pragma unroll
    for (int rq = 0; rq < 4; rq++) {  // reg quads -> 4 consecutive d
      int d = dt * 32 + 8 * rq + 4 * h;
      bf16x4 ov = {(__bf16)(acc[dt][rq * 4 + 0] * inv), (__bf16)(acc[dt][rq * 4 + 1] * inv),
                   (__bf16)(acc[dt][rq * 4 + 2] * inv), (__bf16)(acc[dt][rq * 4 + 3] * inv)};
      *(bf16x4*)(orow + d) = ov;
    }
}

extern "C" void kernel_launch(void* const* d_in, const int* in_sizes, int n_in,
                              void* d_out, int out_size, void* d_ws, size_t ws_size,
                              hipStream_t stream) {
  const float* x  = (const float*)d_in[0];
  // d_in[1] = mask (tril causal; hard-coded in kernel)
  const float* wq = (const float*)d_in[2];
  const float* bq = (const float*)d_in[3];
  const float* wk = (const float*)d_in[4];
  const float* bk = (const float*)d_in[5];
  const float* wv = (const float*)d_in[6];
  const float* bv = (const float*)d_in[7];
  const float* wo = (const float*)d_in[8];
  const float* bo = (const float*)d_in[9];
  float* out = (float*)d_out;

  const size_t MB = 1024 * 1024;
  char* ws = (char*)d_ws;
  __bf16* xb    = (__bf16*)(ws);             //  8 MiB: 2048x2048 (dead after QKV GEMM)
  __bf16* wqkvT = (__bf16*)(ws + 8 * MB);    // 24 MiB (dead after QKV GEMM)
  __bf16* woT   = (__bf16*)(ws + 32 * MB);   // 16 MiB: 2048x4096
  __bf16* qkvb  = (__bf16*)(ws + 48 * MB);   // 24 MiB: 2048x6144
  __bf16* vtb   = (__bf16*)(ws + 72 * MB);   //  4 MiB: 8x128x2048
  __bf16* ob    = (__bf16*)(ws + 76 * MB);   // 16 MiB: 2048x4096
  float*  bqkv  = (float*)(ws + 92 * MB);    // 24 KiB
  float*  Cpart = (float*)(ws);              // 32 MiB: 2x(2048x2048 f32), reuses xb+wqkvT

  k_cvt<<<4096, 256, 0, stream>>>(x, xb, HIDDEN * S_LEN);
  k_transpose_cvt<<<dim3(128, 64), 256, 0, stream>>>(wq, wqkvT, HIDDEN, 4096);
  k_transpose_cvt<<<dim3(32, 64), 256, 0, stream>>>(wk, wqkvT + (size_t)4096 * HIDDEN, HIDDEN, 1024);
  k_transpose_cvt<<<dim3(32, 64), 256, 0, stream>>>(wv, wqkvT + (size_t)5120 * HIDDEN, HIDDEN, 1024);
  k_transpose_cvt<<<dim3(64, 128), 256, 0, stream>>>(wo, woT, 4096, HIDDEN);
  k_bias_concat<<<24, 256, 0, stream>>>(bq, bk, bv, bqkv);

  // QKV projection: 256^2 2-phase/K-tile GEMM (192 blocks, XCD-major m), Q pre-scaled
  k_gemm8<<<192, 512, 0, stream>>>(xb, wqkvT, bqkv, qkvb, S_LEN, QKVN, HIDDEN,
                                   0.08838834764831845f, 4096);
  k_vtrans<<<dim3(S_LEN / 32, HD / 32, NKV), 256, 0, stream>>>(qkvb, vtb);
  k_attn<<<512, 256, 0, stream>>>(qkvb, vtb, ob);
  // O-projection: split-K=2 (512 blocks -> 2 blocks/CU) + combine with bias
  k_gemm_part<<<dim3(HIDDEN / 128, S_LEN / 128, 2), 256, 0, stream>>>(
      ob, woT, Cpart, S_LEN, HIDDEN, OD, OD / 2);
  k_ocombine<<<(S_LEN * HIDDEN) / 1024, 256, 0, stream>>>(
      Cpart, Cpart + (size_t)S_LEN * HIDDEN, bo, out);
}

// Round 16
// 218.344 us; speedup vs baseline: 1.3105x; 1.0804x over previous
//
#include <hip/hip_runtime.h>

#define HIDDEN 2048
#define S_LEN  2048
#define NH     32
#define NKV    8
#define HD     128
#define QKVN   6144   // 4096 q + 1024 k + 1024 v
#define OD     4096   // NH*HD

typedef float  f32x4   __attribute__((ext_vector_type(4)));
typedef float  f32x16  __attribute__((ext_vector_type(16)));
typedef __bf16 bf16x8  __attribute__((ext_vector_type(8)));
typedef __bf16 bf16x4  __attribute__((ext_vector_type(4)));
typedef unsigned int u32;

static __device__ __forceinline__ f32x4 mfma16(bf16x8 a, bf16x8 b, f32x4 c) {
  return __builtin_amdgcn_mfma_f32_16x16x32_bf16(a, b, c, 0, 0, 0);
}
static __device__ __forceinline__ f32x16 mfma32(bf16x8 a, bf16x8 b, f32x16 c) {
  return __builtin_amdgcn_mfma_f32_32x32x16_bf16(a, b, c, 0, 0, 0);
}
static __device__ __forceinline__ void gload_lds16(const void* g, void* l) {
  __builtin_amdgcn_global_load_lds(
      (__attribute__((address_space(1))) void*)(g),
      (__attribute__((address_space(3))) void*)(l), 16, 0, 0);
}
static __device__ __forceinline__ u32 pk_bf16(float lo, float hi) {
  u32 r;
  asm("v_cvt_pk_bf16_f32 %0, %1, %2" : "=v"(r) : "v"(lo), "v"(hi));
  return r;
}

// ---------- fp32 -> bf16 elementwise ----------
__global__ __launch_bounds__(256) void k_cvt(const float* __restrict__ in,
                                             __bf16* __restrict__ out, int n) {
  int i = (blockIdx.x * 256 + threadIdx.x) * 4;
  if (i >= n) return;
  float4 v = *reinterpret_cast<const float4*>(in + i);
  bf16x4 o = {(__bf16)v.x, (__bf16)v.y, (__bf16)v.z, (__bf16)v.w};
  *reinterpret_cast<bf16x4*>(out + i) = o;
}

// ---------- transpose + convert: src (K x N) f32 -> dst (N x K) bf16 ----------
__global__ __launch_bounds__(256) void k_transpose_cvt(const float* __restrict__ src,
                                                       __bf16* __restrict__ dst,
                                                       int K, int N) {
  __shared__ float tile[32][33];
  int tx = threadIdx.x & 31, ty = threadIdx.x >> 5;
  int n0 = blockIdx.x * 32, k0 = blockIdx.y * 32;
#pragma unroll
  for (int r = 0; r < 4; r++) {
    int k = ty + r * 8;
    tile[k][tx] = src[(size_t)(k0 + k) * N + n0 + tx];
  }
  __syncthreads();
#pragma unroll
  for (int r = 0; r < 4; r++) {
    int n = ty + r * 8;
    dst[(size_t)(n0 + n) * K + k0 + tx] = (__bf16)tile[tx][n];
  }
}

__global__ void k_bias_concat(const float* __restrict__ bq, const float* __restrict__ bk,
                              const float* __restrict__ bv, float* __restrict__ out) {
  int i = blockIdx.x * 256 + threadIdx.x;
  if (i >= QKVN) return;
  out[i] = (i < 4096) ? bq[i] : (i < 5120 ? bk[i - 4096] : bv[i - 5120]);
}

// ---------- V transpose: qkv (S x QKVN) v-cols -> vt (NKV x HD x S) ----------
__global__ __launch_bounds__(256) void k_vtrans(const __bf16* __restrict__ qkv,
                                                __bf16* __restrict__ vt) {
  __shared__ __bf16 tile[32][33];
  int tx = threadIdx.x & 31, ty = threadIdx.x >> 5;
  int s0 = blockIdx.x * 32, d0 = blockIdx.y * 32, kv = blockIdx.z;
#pragma unroll
  for (int r = 0; r < 4; r++) {
    int s = ty + r * 8;
    tile[s][tx] = qkv[(size_t)(s0 + s) * QKVN + 5120 + kv * HD + d0 + tx];
  }
  __syncthreads();
#pragma unroll
  for (int r = 0; r < 4; r++) {
    int d = ty + r * 8;
    vt[(size_t)(kv * HD + d0 + d) * S_LEN + s0 + tx] = tile[tx][d];
  }
}

// ---------- 128x192 BK=64 GEMM, 2 phases/K-tile, counted vmcnt (T2+T4+T5) ----------
// C = (A@BT^T + bias)*colscale. 256 threads = 4 waves (1M x 4N); per-wave
// C = 128x48 (8x3 frags 16x16x32), acc[8][3] ~ 96 VGPR.
// LDS 80 KiB: A[2 dbuf][2 kh][128x32] + B[2][2][192x32] -> 2 blocks/CU =
// 100% CU coverage at grid 512 (the 256^2 tile left 25% of CUs idle) plus
// inter-block overlap. XOR swizzle slot^=((row>>1)&3), pre-swizzled source
// (rule #21). Uniform 5 staging loads/thread per K-half -> counted vmcnt(5)
// publishes (wait BEFORE barrier so it covers all waves; r10 race fix);
// last-tile Phase A publishes with vmcnt(0). XCD swizzle: each XCD gets a
// 4-n-tile x all-m slice (3 MB B-slice fits its private L2).
__global__ __launch_bounds__(256, 2) void k_gemm8(const __bf16* __restrict__ A,
                                                  const __bf16* __restrict__ BT,
                                                  const float* __restrict__ bias,
                                                  __bf16* __restrict__ C,
                                                  int M, int N, int K,
                                                  float oscale, int scale_cols) {
  __shared__ __bf16 Al[2][2][4096];   // [dbuf][khalf][128 rows x 32 k]
  __shared__ __bf16 Bl[2][2][6144];   // [dbuf][khalf][192 rows x 32 k]
  const int tid = threadIdx.x, lane = tid & 63, w = tid >> 6;
  const int l15 = lane & 15, lhi = lane >> 4;
  const int sw = ((blockIdx.x & 7) << 6) + (blockIdx.x >> 3);  // XCD-chunked
  const int mt = sw & 15, nt = sw >> 4;
  const int m0 = mt * 128, n0 = nt * 192;
  const int NKT = K >> 6;
  const __bf16* Ab = A + (size_t)m0 * K;
  const __bf16* Bb = BT + (size_t)n0 * K;

  f32x4 acc[8][3];
#pragma unroll
  for (int i = 0; i < 8; i++)
#pragma unroll
    for (int j = 0; j < 3; j++)
#pragma unroll
      for (int e = 0; e < 4; e++) acc[i][j][e] = 0.f;

// stage one K-half: A 2 loads/thread, B 3 loads/thread (uniform; 5 total)
#define SGH(buf, kh, ktile)                                                       \
  do {                                                                            \
    _Pragma("unroll") for (int it = 0; it < 2; ++it) {                            \
      int c = it * 256 + tid;                                                     \
      int row = c >> 2, slot = c & 3;                                             \
      int scol = ((slot * 16) ^ (((row >> 1) & 3) << 4)) >> 1;                    \
      gload_lds16(Ab + (size_t)row * K + (ktile) * 64 + (kh) * 32 + scol,         \
                  &Al[buf][kh][c * 8]);                                           \
    }                                                                             \
    _Pragma("unroll") for (int it = 0; it < 3; ++it) {                            \
      int c = it * 256 + tid;                                                     \
      int row = c >> 2, slot = c & 3;                                             \
      int scol = ((slot * 16) ^ (((row >> 1) & 3) << 4)) >> 1;                    \
      gload_lds16(Bb + (size_t)row * K + (ktile) * 64 + (kh) * 32 + scol,         \
                  &Bl[buf][kh][c * 8]);                                           \
    }                                                                             \
  } while (0)

#define RD_AB(cb, kk)                                                             \
  do {                                                                            \
    _Pragma("unroll") for (int i = 0; i < 8; ++i) {                               \
      int row = i * 16 + l15;                                                     \
      af[i] = *(const bf16x8*)(&Al[cb][kk][row * 32 +                             \
                (((lhi * 16) ^ (((row >> 1) & 3) << 4)) >> 1)]);                  \
    }                                                                             \
    _Pragma("unroll") for (int j = 0; j < 3; ++j) {                               \
      int row = w * 48 + j * 16 + l15;                                            \
      bfr[j] = *(const bf16x8*)(&Bl[cb][kk][row * 32 +                            \
                (((lhi * 16) ^ (((row >> 1) & 3) << 4)) >> 1)]);                  \
    }                                                                             \
  } while (0)

#define MFMA24X                                                                   \
  do {                                                                            \
    __builtin_amdgcn_s_setprio(1);                                                \
    _Pragma("unroll") for (int i = 0; i < 8; ++i) {                               \
      _Pragma("unroll") for (int j = 0; j < 3; ++j) {                             \
        acc[i][j] = mfma16(af[i], bfr[j], acc[i][j]);                             \
      }                                                                           \
    }                                                                             \
    __builtin_amdgcn_s_setprio(0);                                                \
  } while (0)

  // prologue: both K-halves of tile 0 (oldest-first)
  SGH(0, 0, 0);
  SGH(0, 1, 0);
  // PUBLISH K0(0): wait counted loads BEFORE barrier (covers all waves)
  asm volatile("s_waitcnt vmcnt(5)" ::: "memory");
  __builtin_amdgcn_s_barrier();
  __builtin_amdgcn_sched_barrier(0);

  for (int kt = 0; kt < NKT; ++kt) {
    const int cb = kt & 1, pb = cb ^ 1;
    const bool pf = (kt + 1 < NKT);
    bf16x8 af[8], bfr[3];

    // ---- Phase A: K-half 0 (published) ----
    RD_AB(cb, 0);
    if (pf) SGH(pb, 0, kt + 1);
    __builtin_amdgcn_s_barrier();
    asm volatile("s_waitcnt lgkmcnt(0)" ::: "memory");
    MFMA24X;
    if (pf) {
      asm volatile("s_waitcnt vmcnt(5)" ::: "memory");  // K1(cb) landed; K0(next) in flight
    } else {
      asm volatile("s_waitcnt vmcnt(0)" ::: "memory");  // drain K1(last)
    }
    __builtin_amdgcn_s_barrier();   // PUBLISH K1(cb)
    __builtin_amdgcn_sched_barrier(0);

    // ---- Phase B: K-half 1 ----
    RD_AB(cb, 1);
    if (pf) SGH(pb, 1, kt + 1);
    __builtin_amdgcn_s_barrier();
    asm volatile("s_waitcnt lgkmcnt(0)" ::: "memory");
    MFMA24X;
    if (pf) {
      asm volatile("s_waitcnt vmcnt(5)" ::: "memory");  // K0(next) landed; K1(next) in flight
    }
    __builtin_amdgcn_s_barrier();   // PUBLISH K0(next)
    __builtin_amdgcn_sched_barrier(0);
  }
#undef SGH
#undef RD_AB
#undef MFMA24X

  // epilogue
#pragma unroll
  for (int j = 0; j < 3; j++) {
    int col = n0 + w * 48 + j * 16 + l15;
    float bv = bias[col];
    float sc = (col < scale_cols) ? oscale : 1.0f;
#pragma unroll
    for (int i = 0; i < 8; i++) {
      int r0 = m0 + i * 16 + lhi * 4;
#pragma unroll
      for (int rr = 0; rr < 4; rr++) {
        C[(size_t)(r0 + rr) * N + col] = (__bf16)((acc[i][j][rr] + bv) * sc);
      }
    }
  }
}

// ---------- split-K GEMM partial: Cpart[z] (MxN f32) = A @ BT^T over K-chunk z ----------
__global__ __launch_bounds__(256) void k_gemm_part(const __bf16* __restrict__ A,
                                                   const __bf16* __restrict__ BT,
                                                   float* __restrict__ Cpart,
                                                   int M, int N, int K, int KC) {
  __shared__ __bf16 Al[128 * 64];
  __shared__ __bf16 Bl[128 * 64];
  const int tid = threadIdx.x;
  const int lane = tid & 63;
  const int w = tid >> 6;
  const int m0 = blockIdx.y * 128;
  const int n0 = blockIdx.x * 128;
  const int kbeg = blockIdx.z * KC;
  const int wm = (w >> 1) * 64;
  const int wn = (w & 1) * 64;
  const int l15 = lane & 15, lhi = lane >> 4;

  f32x4 acc[4][4];
#pragma unroll
  for (int i = 0; i < 4; i++)
#pragma unroll
    for (int j = 0; j < 4; j++)
#pragma unroll
      for (int e = 0; e < 4; e++) acc[i][j][e] = 0.f;

  for (int kt = kbeg; kt < kbeg + KC; kt += 64) {
#pragma unroll
    for (int it = 0; it < 4; it++) {
      int idx = it * 256 + tid;
      int row = idx >> 3, slot = idx & 7;
      int scol = ((slot * 16) ^ ((row & 7) << 4)) >> 1;
      gload_lds16(A + (size_t)(m0 + row) * K + kt + scol, &Al[idx * 8]);
      gload_lds16(BT + (size_t)(n0 + row) * K + kt + scol, &Bl[idx * 8]);
    }
    __syncthreads();
#pragma unroll
    for (int kk = 0; kk < 2; kk++) {
      bf16x8 af[4], bfr[4];
#pragma unroll
      for (int i = 0; i < 4; i++) {
        int ra = wm + i * 16 + l15;
        int ba = (kk * 64 + lhi * 16) ^ ((ra & 7) << 4);
        af[i] = *(const bf16x8*)((const char*)Al + ra * 128 + ba);
        int rb = wn + i * 16 + l15;
        int bb = (kk * 64 + lhi * 16) ^ ((rb & 7) << 4);
        bfr[i] = *(const bf16x8*)((const char*)Bl + rb * 128 + bb);
      }
#pragma unroll
      for (int i = 0; i < 4; i++)
#pragma unroll
        for (int j = 0; j < 4; j++) acc[i][j] = mfma16(af[i], bfr[j], acc[i][j]);
    }
    __syncthreads();
  }
  float* C = Cpart + (size_t)blockIdx.z * M * N;
#pragma unroll
  for (int j = 0; j < 4; j++) {
    int col = n0 + wn + j * 16 + l15;
#pragma unroll
    for (int i = 0; i < 4; i++) {
      int r0 = m0 + wm + i * 16 + lhi * 4;
#pragma unroll
      for (int rr = 0; rr < 4; rr++) {
        C[(size_t)(r0 + rr) * N + col] = acc[i][j][rr];
      }
    }
  }
}

// ---------- combine split-K partials + bias -> f32 out ----------
__global__ __launch_bounds__(256) void k_ocombine(const float* __restrict__ a,
                                                  const float* __restrict__ b,
                                                  const float* __restrict__ bias,
                                                  float* __restrict__ out) {
  int i = (blockIdx.x * 256 + threadIdx.x) * 4;
  f32x4 va = *(const f32x4*)(a + i);
  f32x4 vb = *(const f32x4*)(b + i);
  f32x4 vbias = *(const f32x4*)(bias + (i & (HIDDEN - 1)));
  f32x4 r = va + vb + vbias;
  *(f32x4*)(out + i) = r;
}

// ---------- causal GQA flash attention (r12 state: anti-pairing + dbuf K/V) ----------
// 512 blocks, 256 threads; ids i and i+256 get tiles t and 15-t. 4 waves x 32
// q-rows. Double-buffered K/V (64 KiB), coalesced staging with pre-swizzled
// source (rule #21). S^T = mfma(K,Q) so q = lane&31 (softmax lane-local);
// P in registers via cvt_pk + permlane32_swap; O^T = mfma(V^T, P).
//   Kl[key][d]: byte = key*256 + ((2d) ^ ((key&15)<<4))   (reads 2-way, free)
//   Vl[d][k]:   byte = d*128  + ((2k) ^ ((d&7)<<4))       (reads 4-way, 1.58x)
__global__ __launch_bounds__(256, 2) void k_attn(const __bf16* __restrict__ qkv,
                                                 const __bf16* __restrict__ vt,
                                                 __bf16* __restrict__ o) {
  __shared__ __bf16 Kl[2][8192];
  __shared__ __bf16 Vl[2][8192];
  const int tid = threadIdx.x, lane = tid & 63, w = tid >> 6;
  const int l31 = lane & 31, h = lane >> 5;

  // block-id pairing: ids i and i+256 get tiles t and 15-t (uniform CU load)
  const int id = blockIdx.x;
  int tile, head;
  if (id < 256) { head = id >> 4; tile = id & 15; }
  else          { head = 16 + ((id - 256) >> 4); tile = 15 - (id & 15); }
  const int kvh = head >> 2;
  const int qbase = tile * 128 + w * 32;
  const int qg = qbase + l31;          // this lane's q row
  const int kdiag = (qbase + 31) >> 6; // last (partial) key tile for this wave
  const int nkt = 2 * tile + 2;

  // Q fragments (pre-scaled by 1/sqrt(d) in QKV GEMM epilogue): B-frag col=q
  bf16x8 qf[8];
  {
    const __bf16* qrow = qkv + (size_t)qg * QKVN + head * HD;
#pragma unroll
    for (int dk = 0; dk < 8; dk++) qf[dk] = *(const bf16x8*)(qrow + dk * 16 + h * 8);
  }

  f32x16 acc[4];  // O^T: col=q=lane&31, row=d (reg-mapped), dt*32 block
#pragma unroll
  for (int dt = 0; dt < 4; dt++)
#pragma unroll
    for (int r = 0; r < 16; r++) acc[dt][r] = 0.f;
  float m = -INFINITY, lsum = 0.f;

#define STAGE(buf, ktile)                                                           \
  do {                                                                              \
    const int kk0 = (ktile) * 64;                                                   \
    _Pragma("unroll") for (int it = 0; it < 4; it++) {                              \
      int c = it * 256 + tid;                                                       \
      int key = c >> 4, slot = c & 15;                                              \
      int scol = ((slot * 16) ^ ((key & 15) << 4)) >> 1;                            \
      gload_lds16(qkv + (size_t)(kk0 + key) * QKVN + 4096 + kvh * HD + scol,        \
                  &Kl[buf][c * 8]);                                                 \
    }                                                                               \
    _Pragma("unroll") for (int it = 0; it < 4; it++) {                              \
      int c = it * 256 + tid;                                                       \
      int d = c >> 3, slot = c & 7;                                                 \
      int scol = ((slot * 16) ^ ((d & 7) << 4)) >> 1;                               \
      gload_lds16(vt + (size_t)(kvh * HD + d) * S_LEN + kk0 + scol,                 \
                  &Vl[buf][c * 8]);                                                 \
    }                                                                               \
  } while (0)

  STAGE(0, 0);
  __syncthreads();

  for (int kt = 0; kt < nkt; kt++) {
    const int cur = kt & 1;
    if (kt + 1 < nkt) STAGE(cur ^ 1, kt + 1);  // in flight during compute

    if (kt <= kdiag) {
      const char* Kb = (const char*)&Kl[cur][0];
      const char* Vb = (const char*)&Vl[cur][0];
      const int k0 = kt * 64;
      // ---- QK^T: S^T[key][q], two 32-key blocks ----
      f32x16 sacc[2];
#pragma unroll
      for (int b = 0; b < 2; b++)
#pragma unroll
        for (int r = 0; r < 16; r++) sacc[b][r] = 0.f;
      __builtin_amdgcn_s_setprio(1);
#pragma unroll
      for (int dk = 0; dk < 8; dk++) {
        const int sA = ((2 * dk + h) ^ (l31 & 15)) * 16;
        bf16x8 kf0 = *(const bf16x8*)(Kb + l31 * 256 + sA);
        bf16x8 kf1 = *(const bf16x8*)(Kb + (32 + l31) * 256 + sA);
        sacc[0] = mfma32(kf0, qf[dk], sacc[0]);
        sacc[1] = mfma32(kf1, qf[dk], sacc[1]);
      }
      __builtin_amdgcn_s_setprio(0);
      // ---- softmax (lane-local; q = lane&31) ----
      float p[32];
#pragma unroll
      for (int b = 0; b < 2; b++)
#pragma unroll
        for (int r = 0; r < 16; r++) p[b * 16 + r] = sacc[b][r];
      if (kt == kdiag) {  // mask only on the diagonal tile
#pragma unroll
        for (int b = 0; b < 2; b++)
#pragma unroll
          for (int r = 0; r < 16; r++) {
            int keyg = k0 + b * 32 + (r & 3) + 8 * (r >> 2) + 4 * h;
            if (keyg > qg) p[b * 16 + r] = -INFINITY;
          }
      }
      // pairwise max tree (depth 5)
      float t16[16], t8[8], t4[4];
#pragma unroll
      for (int i = 0; i < 16; i++) t16[i] = fmaxf(p[2 * i], p[2 * i + 1]);
#pragma unroll
      for (int i = 0; i < 8; i++) t8[i] = fmaxf(t16[2 * i], t16[2 * i + 1]);
#pragma unroll
      for (int i = 0; i < 4; i++) t4[i] = fmaxf(t8[2 * i], t8[2 * i + 1]);
      float pm = fmaxf(fmaxf(t4[0], t4[1]), fmaxf(t4[2], t4[3]));
      pm = fmaxf(pm, __shfl_xor(pm, 32));
      if (__any(pm - m > 8.f)) {  // defer-max (T13)
        float mn = fmaxf(m, pm);
        float corr = __expf(m - mn);
        m = mn;
        lsum *= corr;
#pragma unroll
        for (int dt = 0; dt < 4; dt++)
#pragma unroll
          for (int r = 0; r < 16; r++) acc[dt][r] *= corr;
      }
      float psum = 0.f;
#pragma unroll
      for (int i = 0; i < 32; i++) { p[i] = __expf(p[i] - m); psum += p[i]; }
      lsum += psum;
      // ---- PV: O^T += V^T * P, P-frags built in-register ----
      // permlane32_swap(W0,W2): W0 -> {lo:W0@h0, hi:W2@h0}, W2 -> {lo:W0@h1, hi:W2@h1}.
#pragma unroll
      for (int ks2 = 0; ks2 < 4; ks2++) {
        const int o8 = (ks2 >> 1) * 16 + (ks2 & 1) * 8;
        u32 W0 = pk_bf16(p[o8 + 0], p[o8 + 1]);
        u32 W1 = pk_bf16(p[o8 + 2], p[o8 + 3]);
        u32 W2 = pk_bf16(p[o8 + 4], p[o8 + 5]);
        u32 W3 = pk_bf16(p[o8 + 6], p[o8 + 7]);
        asm("v_permlane32_swap_b32 %0, %1" : "+v"(W0), "+v"(W2));
        asm("v_permlane32_swap_b32 %0, %1" : "+v"(W1), "+v"(W3));
        union { u32 wd[4]; bf16x8 v; } pu;
        pu.wd[0] = W0; pu.wd[1] = W1; pu.wd[2] = W2; pu.wd[3] = W3;
        __builtin_amdgcn_s_setprio(1);
#pragma unroll
        for (int dt = 0; dt < 4; dt++) {
          const int dr = dt * 32 + l31;
          const int sV = ((2 * ks2 + h) ^ (dr & 7)) * 16;
          bf16x8 vf = *(const bf16x8*)(Vb + dr * 128 + sV);
          acc[dt] = mfma32(vf, pu.v, acc[dt]);
        }
        __builtin_amdgcn_s_setprio(0);
      }
    }
    __syncthreads();  // drains vmcnt: next tile landed; buffers safe to swap
  }
#undef STAGE

  // ---- finalize: combine the two key-halves, normalize, store ----
  lsum += __shfl_xor(lsum, 32);
  const float inv = 1.f / lsum;
  __bf16* orow = o + (size_t)qg * OD + head * HD;
#pragma unroll
  for (int dt = 0; dt < 4; dt++)
#pragma unroll
    for (int rq = 0; rq < 4; rq++) {  // reg quads -> 4 consecutive d
      int d = dt * 32 + 8 * rq + 4 * h;
      bf16x4 ov = {(__bf16)(acc[dt][rq * 4 + 0] * inv), (__bf16)(acc[dt][rq * 4 + 1] * inv),
                   (__bf16)(acc[dt][rq * 4 + 2] * inv), (__bf16)(acc[dt][rq * 4 + 3] * inv)};
      *(bf16x4*)(orow + d) = ov;
    }
}

extern "C" void kernel_launch(void* const* d_in, const int* in_sizes, int n_in,
                              void* d_out, int out_size, void* d_ws, size_t ws_size,
                              hipStream_t stream) {
  const float* x  = (const float*)d_in[0];
  // d_in[1] = mask (tril causal; hard-coded in kernel)
  const float* wq = (const float*)d_in[2];
  const float* bq = (const float*)d_in[3];
  const float* wk = (const float*)d_in[4];
  const float* bk = (const float*)d_in[5];
  const float* wv = (const float*)d_in[6];
  const float* bv = (const float*)d_in[7];
  const float* wo = (const float*)d_in[8];
  const float* bo = (const float*)d_in[9];
  float* out = (float*)d_out;

  const size_t MB = 1024 * 1024;
  char* ws = (char*)d_ws;
  __bf16* xb    = (__bf16*)(ws);             //  8 MiB: 2048x2048 (dead after QKV GEMM)
  __bf16* wqkvT = (__bf16*)(ws + 8 * MB);    // 24 MiB (dead after QKV GEMM)
  __bf16* woT   = (__bf16*)(ws + 32 * MB);   // 16 MiB: 2048x4096
  __bf16* qkvb  = (__bf16*)(ws + 48 * MB);   // 24 MiB: 2048x6144
  __bf16* vtb   = (__bf16*)(ws + 72 * MB);   //  4 MiB: 8x128x2048
  __bf16* ob    = (__bf16*)(ws + 76 * MB);   // 16 MiB: 2048x4096
  float*  bqkv  = (float*)(ws + 92 * MB);    // 24 KiB
  float*  Cpart = (float*)(ws);              // 32 MiB: 2x(2048x2048 f32), reuses xb+wqkvT

  k_cvt<<<4096, 256, 0, stream>>>(x, xb, HIDDEN * S_LEN);
  k_transpose_cvt<<<dim3(128, 64), 256, 0, stream>>>(wq, wqkvT, HIDDEN, 4096);
  k_transpose_cvt<<<dim3(32, 64), 256, 0, stream>>>(wk, wqkvT + (size_t)4096 * HIDDEN, HIDDEN, 1024);
  k_transpose_cvt<<<dim3(32, 64), 256, 0, stream>>>(wv, wqkvT + (size_t)5120 * HIDDEN, HIDDEN, 1024);
  k_transpose_cvt<<<dim3(64, 128), 256, 0, stream>>>(wo, woT, 4096, HIDDEN);
  k_bias_concat<<<24, 256, 0, stream>>>(bq, bk, bv, bqkv);

  // QKV projection: 128x192 2-phase GEMM (512 blocks = 2/CU, full coverage)
  k_gemm8<<<512, 256, 0, stream>>>(xb, wqkvT, bqkv, qkvb, S_LEN, QKVN, HIDDEN,
                                   0.08838834764831845f, 4096);
  k_vtrans<<<dim3(S_LEN / 32, HD / 32, NKV), 256, 0, stream>>>(qkvb, vtb);
  k_attn<<<512, 256, 0, stream>>>(qkvb, vtb, ob);
  // O-projection: split-K=2 (512 blocks -> 2 blocks/CU) + combine with bias
  k_gemm_part<<<dim3(HIDDEN / 128, S_LEN / 128, 2), 256, 0, stream>>>(
      ob, woT, Cpart, S_LEN, HIDDEN, OD, OD / 2);
  k_ocombine<<<(S_LEN * HIDDEN) / 1024, 256, 0, stream>>>(
      Cpart, Cpart + (size_t)S_LEN * HIDDEN, bo, out);
}

// Round 17
// 218.151 us; speedup vs baseline: 1.3116x; 1.0009x over previous
//
#include <hip/hip_runtime.h>

#define HIDDEN 2048
#define S_LEN  2048
#define NH     32
#define NKV    8
#define HD     128
#define QKVN   6144   // 4096 q + 1024 k + 1024 v
#define OD     4096   // NH*HD

typedef float  f32x4   __attribute__((ext_vector_type(4)));
typedef float  f32x16  __attribute__((ext_vector_type(16)));
typedef __bf16 bf16x8  __attribute__((ext_vector_type(8)));
typedef __bf16 bf16x4  __attribute__((ext_vector_type(4)));
typedef unsigned int u32;

static __device__ __forceinline__ f32x4 mfma16(bf16x8 a, bf16x8 b, f32x4 c) {
  return __builtin_amdgcn_mfma_f32_16x16x32_bf16(a, b, c, 0, 0, 0);
}
static __device__ __forceinline__ f32x16 mfma32(bf16x8 a, bf16x8 b, f32x16 c) {
  return __builtin_amdgcn_mfma_f32_32x32x16_bf16(a, b, c, 0, 0, 0);
}
static __device__ __forceinline__ void gload_lds16(const void* g, void* l) {
  __builtin_amdgcn_global_load_lds(
      (__attribute__((address_space(1))) void*)(g),
      (__attribute__((address_space(3))) void*)(l), 16, 0, 0);
}
static __device__ __forceinline__ u32 pk_bf16(float lo, float hi) {
  u32 r;
  asm("v_cvt_pk_bf16_f32 %0, %1, %2" : "=v"(r) : "v"(lo), "v"(hi));
  return r;
}

// ---------- fp32 -> bf16 elementwise ----------
__global__ __launch_bounds__(256) void k_cvt(const float* __restrict__ in,
                                             __bf16* __restrict__ out, int n) {
  int i = (blockIdx.x * 256 + threadIdx.x) * 4;
  if (i >= n) return;
  float4 v = *reinterpret_cast<const float4*>(in + i);
  bf16x4 o = {(__bf16)v.x, (__bf16)v.y, (__bf16)v.z, (__bf16)v.w};
  *reinterpret_cast<bf16x4*>(out + i) = o;
}

// ---------- transpose + convert: src (K x N) f32 -> dst (N x K) bf16 ----------
__global__ __launch_bounds__(256) void k_transpose_cvt(const float* __restrict__ src,
                                                       __bf16* __restrict__ dst,
                                                       int K, int N) {
  __shared__ float tile[32][33];
  int tx = threadIdx.x & 31, ty = threadIdx.x >> 5;
  int n0 = blockIdx.x * 32, k0 = blockIdx.y * 32;
#pragma unroll
  for (int r = 0; r < 4; r++) {
    int k = ty + r * 8;
    tile[k][tx] = src[(size_t)(k0 + k) * N + n0 + tx];
  }
  __syncthreads();
#pragma unroll
  for (int r = 0; r < 4; r++) {
    int n = ty + r * 8;
    dst[(size_t)(n0 + n) * K + k0 + tx] = (__bf16)tile[tx][n];
  }
}

__global__ void k_bias_concat(const float* __restrict__ bq, const float* __restrict__ bk,
                              const float* __restrict__ bv, float* __restrict__ out) {
  int i = blockIdx.x * 256 + threadIdx.x;
  if (i >= QKVN) return;
  out[i] = (i < 4096) ? bq[i] : (i < 5120 ? bk[i - 4096] : bv[i - 5120]);
}

// ---------- V transpose: qkv (S x QKVN) v-cols -> vt (NKV x HD x S) ----------
__global__ __launch_bounds__(256) void k_vtrans(const __bf16* __restrict__ qkv,
                                                __bf16* __restrict__ vt) {
  __shared__ __bf16 tile[32][33];
  int tx = threadIdx.x & 31, ty = threadIdx.x >> 5;
  int s0 = blockIdx.x * 32, d0 = blockIdx.y * 32, kv = blockIdx.z;
#pragma unroll
  for (int r = 0; r < 4; r++) {
    int s = ty + r * 8;
    tile[s][tx] = qkv[(size_t)(s0 + s) * QKVN + 5120 + kv * HD + d0 + tx];
  }
  __syncthreads();
#pragma unroll
  for (int r = 0; r < 4; r++) {
    int d = ty + r * 8;
    vt[(size_t)(kv * HD + d0 + d) * S_LEN + s0 + tx] = tile[tx][d];
  }
}

// ---------- 128x192 BK=64 GEMM, 2 phases/K-tile, counted vmcnt (T2+T4+T5) ----------
// C = (A@BT^T + bias)*colscale. 256 threads = 4 waves (1M x 4N); per-wave
// C = 128x48 (8x3 frags 16x16x32), acc[8][3] ~ 96 VGPR.
// LDS 80 KiB -> 2 blocks/CU = full coverage at grid 512. XOR swizzle
// slot^=((row>>1)&3), pre-swizzled source (rule #21). Uniform 5 staging
// loads/thread per K-half -> counted vmcnt(5) publishes (wait BEFORE barrier).
__global__ __launch_bounds__(256, 2) void k_gemm8(const __bf16* __restrict__ A,
                                                  const __bf16* __restrict__ BT,
                                                  const float* __restrict__ bias,
                                                  __bf16* __restrict__ C,
                                                  int M, int N, int K,
                                                  float oscale, int scale_cols) {
  __shared__ __bf16 Al[2][2][4096];   // [dbuf][khalf][128 rows x 32 k]
  __shared__ __bf16 Bl[2][2][6144];   // [dbuf][khalf][192 rows x 32 k]
  const int tid = threadIdx.x, lane = tid & 63, w = tid >> 6;
  const int l15 = lane & 15, lhi = lane >> 4;
  const int sw = ((blockIdx.x & 7) << 6) + (blockIdx.x >> 3);  // XCD-chunked
  const int mt = sw & 15, nt = sw >> 4;
  const int m0 = mt * 128, n0 = nt * 192;
  const int NKT = K >> 6;
  const __bf16* Ab = A + (size_t)m0 * K;
  const __bf16* Bb = BT + (size_t)n0 * K;

  f32x4 acc[8][3];
#pragma unroll
  for (int i = 0; i < 8; i++)
#pragma unroll
    for (int j = 0; j < 3; j++)
#pragma unroll
      for (int e = 0; e < 4; e++) acc[i][j][e] = 0.f;

#define SGH(buf, kh, ktile)                                                       \
  do {                                                                            \
    _Pragma("unroll") for (int it = 0; it < 2; ++it) {                            \
      int c = it * 256 + tid;                                                     \
      int row = c >> 2, slot = c & 3;                                             \
      int scol = ((slot * 16) ^ (((row >> 1) & 3) << 4)) >> 1;                    \
      gload_lds16(Ab + (size_t)row * K + (ktile) * 64 + (kh) * 32 + scol,         \
                  &Al[buf][kh][c * 8]);                                           \
    }                                                                             \
    _Pragma("unroll") for (int it = 0; it < 3; ++it) {                            \
      int c = it * 256 + tid;                                                     \
      int row = c >> 2, slot = c & 3;                                             \
      int scol = ((slot * 16) ^ (((row >> 1) & 3) << 4)) >> 1;                    \
      gload_lds16(Bb + (size_t)row * K + (ktile) * 64 + (kh) * 32 + scol,         \
                  &Bl[buf][kh][c * 8]);                                           \
    }                                                                             \
  } while (0)

#define RD_AB(cb, kk)                                                             \
  do {                                                                            \
    _Pragma("unroll") for (int i = 0; i < 8; ++i) {                               \
      int row = i * 16 + l15;                                                     \
      af[i] = *(const bf16x8*)(&Al[cb][kk][row * 32 +                             \
                (((lhi * 16) ^ (((row >> 1) & 3) << 4)) >> 1)]);                  \
    }                                                                             \
    _Pragma("unroll") for (int j = 0; j < 3; ++j) {                               \
      int row = w * 48 + j * 16 + l15;                                            \
      bfr[j] = *(const bf16x8*)(&Bl[cb][kk][row * 32 +                            \
                (((lhi * 16) ^ (((row >> 1) & 3) << 4)) >> 1)]);                  \
    }                                                                             \
  } while (0)

#define MFMA24X                                                                   \
  do {                                                                            \
    __builtin_amdgcn_s_setprio(1);                                                \
    _Pragma("unroll") for (int i = 0; i < 8; ++i) {                               \
      _Pragma("unroll") for (int j = 0; j < 3; ++j) {                             \
        acc[i][j] = mfma16(af[i], bfr[j], acc[i][j]);                             \
      }                                                                           \
    }                                                                             \
    __builtin_amdgcn_s_setprio(0);                                                \
  } while (0)

  SGH(0, 0, 0);
  SGH(0, 1, 0);
  asm volatile("s_waitcnt vmcnt(5)" ::: "memory");
  __builtin_amdgcn_s_barrier();
  __builtin_amdgcn_sched_barrier(0);

  for (int kt = 0; kt < NKT; ++kt) {
    const int cb = kt & 1, pb = cb ^ 1;
    const bool pf = (kt + 1 < NKT);
    bf16x8 af[8], bfr[3];

    RD_AB(cb, 0);
    if (pf) SGH(pb, 0, kt + 1);
    __builtin_amdgcn_s_barrier();
    asm volatile("s_waitcnt lgkmcnt(0)" ::: "memory");
    MFMA24X;
    if (pf) {
      asm volatile("s_waitcnt vmcnt(5)" ::: "memory");
    } else {
      asm volatile("s_waitcnt vmcnt(0)" ::: "memory");
    }
    __builtin_amdgcn_s_barrier();
    __builtin_amdgcn_sched_barrier(0);

    RD_AB(cb, 1);
    if (pf) SGH(pb, 1, kt + 1);
    __builtin_amdgcn_s_barrier();
    asm volatile("s_waitcnt lgkmcnt(0)" ::: "memory");
    MFMA24X;
    if (pf) {
      asm volatile("s_waitcnt vmcnt(5)" ::: "memory");
    }
    __builtin_amdgcn_s_barrier();
    __builtin_amdgcn_sched_barrier(0);
  }
#undef SGH
#undef RD_AB
#undef MFMA24X

#pragma unroll
  for (int j = 0; j < 3; j++) {
    int col = n0 + w * 48 + j * 16 + l15;
    float bv = bias[col];
    float sc = (col < scale_cols) ? oscale : 1.0f;
#pragma unroll
    for (int i = 0; i < 8; i++) {
      int r0 = m0 + i * 16 + lhi * 4;
#pragma unroll
      for (int rr = 0; rr < 4; rr++) {
        C[(size_t)(r0 + rr) * N + col] = (__bf16)((acc[i][j][rr] + bv) * sc);
      }
    }
  }
}

// ---------- split-K O-GEMM partial, 2-phase counted-vmcnt dbuf (ported schedule) ----------
// Cpart[z] (MxN f32) = A @ BT^T over K-chunk z. 128x128/BK=64, 256 thr = 4
// waves (1M x 4N); per-wave C = 128x32 (8x2 frags), acc[8][2]. LDS 64 KiB
// (A/B [2 dbuf][2 kh][128x32]) -> 2 blocks/CU at grid 512 (both chunks).
// Uniform 4 staging loads/thread per K-half -> counted vmcnt(4) publishes
// executed BEFORE the barrier (covers all waves; r10 race fix); last tile
// drains vmcnt(0). XCD-chunked swizzle within each K-chunk.
__global__ __launch_bounds__(256, 2) void k_gemm_part(const __bf16* __restrict__ A,
                                                      const __bf16* __restrict__ BT,
                                                      float* __restrict__ Cpart,
                                                      int M, int N, int K, int KC) {
  __shared__ __bf16 Al[2][2][4096];   // [dbuf][khalf][128 rows x 32 k]
  __shared__ __bf16 Bl[2][2][4096];
  const int tid = threadIdx.x, lane = tid & 63, w = tid >> 6;
  const int l15 = lane & 15, lhi = lane >> 4;
  const int bid = blockIdx.x;
  const int z = bid >> 8, rem = bid & 255;
  const int sw = ((rem & 7) << 5) + (rem >> 3);  // XCD-chunked, bijective on 256
  const int mt = sw & 15, nt = sw >> 4;
  const int m0 = mt * 128, n0 = nt * 128;
  const int NKT = KC >> 6;
  const __bf16* Ab = A + (size_t)m0 * K + (size_t)z * KC;
  const __bf16* Bb = BT + (size_t)n0 * K + (size_t)z * KC;

  f32x4 acc[8][2];
#pragma unroll
  for (int i = 0; i < 8; i++)
#pragma unroll
    for (int j = 0; j < 2; j++)
#pragma unroll
      for (int e = 0; e < 4; e++) acc[i][j][e] = 0.f;

#define SGH2(buf, kh, ktile)                                                      \
  do {                                                                            \
    _Pragma("unroll") for (int it = 0; it < 2; ++it) {                            \
      int c = it * 256 + tid;                                                     \
      int row = c >> 2, slot = c & 3;                                             \
      int scol = ((slot * 16) ^ (((row >> 1) & 3) << 4)) >> 1;                    \
      gload_lds16(Ab + (size_t)row * K + (ktile) * 64 + (kh) * 32 + scol,         \
                  &Al[buf][kh][c * 8]);                                           \
    }                                                                             \
    _Pragma("unroll") for (int it = 0; it < 2; ++it) {                            \
      int c = it * 256 + tid;                                                     \
      int row = c >> 2, slot = c & 3;                                             \
      int scol = ((slot * 16) ^ (((row >> 1) & 3) << 4)) >> 1;                    \
      gload_lds16(Bb + (size_t)row * K + (ktile) * 64 + (kh) * 32 + scol,         \
                  &Bl[buf][kh][c * 8]);                                           \
    }                                                                             \
  } while (0)

#define RD_AB2(cb, kk)                                                            \
  do {                                                                            \
    _Pragma("unroll") for (int i = 0; i < 8; ++i) {                               \
      int row = i * 16 + l15;                                                     \
      af[i] = *(const bf16x8*)(&Al[cb][kk][row * 32 +                             \
                (((lhi * 16) ^ (((row >> 1) & 3) << 4)) >> 1)]);                  \
    }                                                                             \
    _Pragma("unroll") for (int j = 0; j < 2; ++j) {                               \
      int row = w * 32 + j * 16 + l15;                                            \
      bfr[j] = *(const bf16x8*)(&Bl[cb][kk][row * 32 +                            \
                (((lhi * 16) ^ (((row >> 1) & 3) << 4)) >> 1)]);                  \
    }                                                                             \
  } while (0)

#define MFMA16X                                                                   \
  do {                                                                            \
    __builtin_amdgcn_s_setprio(1);                                                \
    _Pragma("unroll") for (int i = 0; i < 8; ++i) {                               \
      _Pragma("unroll") for (int j = 0; j < 2; ++j) {                             \
        acc[i][j] = mfma16(af[i], bfr[j], acc[i][j]);                             \
      }                                                                           \
    }                                                                             \
    __builtin_amdgcn_s_setprio(0);                                                \
  } while (0)

  SGH2(0, 0, 0);
  SGH2(0, 1, 0);
  asm volatile("s_waitcnt vmcnt(4)" ::: "memory");
  __builtin_amdgcn_s_barrier();
  __builtin_amdgcn_sched_barrier(0);

  for (int kt = 0; kt < NKT; ++kt) {
    const int cb = kt & 1, pb = cb ^ 1;
    const bool pf = (kt + 1 < NKT);
    bf16x8 af[8], bfr[2];

    // ---- Phase A: K-half 0 ----
    RD_AB2(cb, 0);
    if (pf) SGH2(pb, 0, kt + 1);
    __builtin_amdgcn_s_barrier();
    asm volatile("s_waitcnt lgkmcnt(0)" ::: "memory");
    MFMA16X;
    if (pf) {
      asm volatile("s_waitcnt vmcnt(4)" ::: "memory");
    } else {
      asm volatile("s_waitcnt vmcnt(0)" ::: "memory");
    }
    __builtin_amdgcn_s_barrier();
    __builtin_amdgcn_sched_barrier(0);

    // ---- Phase B: K-half 1 ----
    RD_AB2(cb, 1);
    if (pf) SGH2(pb, 1, kt + 1);
    __builtin_amdgcn_s_barrier();
    asm volatile("s_waitcnt lgkmcnt(0)" ::: "memory");
    MFMA16X;
    if (pf) {
      asm volatile("s_waitcnt vmcnt(4)" ::: "memory");
    }
    __builtin_amdgcn_s_barrier();
    __builtin_amdgcn_sched_barrier(0);
  }
#undef SGH2
#undef RD_AB2
#undef MFMA16X

  float* C = Cpart + (size_t)z * M * N;
#pragma unroll
  for (int j = 0; j < 2; j++) {
    int col = n0 + w * 32 + j * 16 + l15;
#pragma unroll
    for (int i = 0; i < 8; i++) {
      int r0 = m0 + i * 16 + lhi * 4;
#pragma unroll
      for (int rr = 0; rr < 4; rr++) {
        C[(size_t)(r0 + rr) * N + col] = acc[i][j][rr];
      }
    }
  }
}

// ---------- combine split-K partials + bias -> f32 out ----------
__global__ __launch_bounds__(256) void k_ocombine(const float* __restrict__ a,
                                                  const float* __restrict__ b,
                                                  const float* __restrict__ bias,
                                                  float* __restrict__ out) {
  int i = (blockIdx.x * 256 + threadIdx.x) * 4;
  f32x4 va = *(const f32x4*)(a + i);
  f32x4 vb = *(const f32x4*)(b + i);
  f32x4 vbias = *(const f32x4*)(bias + (i & (HIDDEN - 1)));
  f32x4 r = va + vb + vbias;
  *(f32x4*)(out + i) = r;
}

// ---------- causal GQA flash attention (r12 state: anti-pairing + dbuf K/V) ----------
// 512 blocks, 256 threads; ids i and i+256 get tiles t and 15-t. 4 waves x 32
// q-rows. Double-buffered K/V (64 KiB), coalesced staging with pre-swizzled
// source (rule #21). S^T = mfma(K,Q) so q = lane&31 (softmax lane-local);
// P in registers via cvt_pk + permlane32_swap; O^T = mfma(V^T, P).
//   Kl[key][d]: byte = key*256 + ((2d) ^ ((key&15)<<4))   (reads 2-way, free)
//   Vl[d][k]:   byte = d*128  + ((2k) ^ ((d&7)<<4))       (reads 4-way, 1.58x)
__global__ __launch_bounds__(256, 2) void k_attn(const __bf16* __restrict__ qkv,
                                                 const __bf16* __restrict__ vt,
                                                 __bf16* __restrict__ o) {
  __shared__ __bf16 Kl[2][8192];
  __shared__ __bf16 Vl[2][8192];
  const int tid = threadIdx.x, lane = tid & 63, w = tid >> 6;
  const int l31 = lane & 31, h = lane >> 5;

  // block-id pairing: ids i and i+256 get tiles t and 15-t (uniform CU load)
  const int id = blockIdx.x;
  int tile, head;
  if (id < 256) { head = id >> 4; tile = id & 15; }
  else          { head = 16 + ((id - 256) >> 4); tile = 15 - (id & 15); }
  const int kvh = head >> 2;
  const int qbase = tile * 128 + w * 32;
  const int qg = qbase + l31;          // this lane's q row
  const int kdiag = (qbase + 31) >> 6; // last (partial) key tile for this wave
  const int nkt = 2 * tile + 2;

  // Q fragments (pre-scaled by 1/sqrt(d) in QKV GEMM epilogue): B-frag col=q
  bf16x8 qf[8];
  {
    const __bf16* qrow = qkv + (size_t)qg * QKVN + head * HD;
#pragma unroll
    for (int dk = 0; dk < 8; dk++) qf[dk] = *(const bf16x8*)(qrow + dk * 16 + h * 8);
  }

  f32x16 acc[4];  // O^T: col=q=lane&31, row=d (reg-mapped), dt*32 block
#pragma unroll
  for (int dt = 0; dt < 4; dt++)
#pragma unroll
    for (int r = 0; r < 16; r++) acc[dt][r] = 0.f;
  float m = -INFINITY, lsum = 0.f;

#define STAGE(buf, ktile)                                                           \
  do {                                                                              \
    const int kk0 = (ktile) * 64;                                                   \
    _Pragma("unroll") for (int it = 0; it < 4; it++) {                              \
      int c = it * 256 + tid;                                                       \
      int key = c >> 4, slot = c & 15;                                              \
      int scol = ((slot * 16) ^ ((key & 15) << 4)) >> 1;                            \
      gload_lds16(qkv + (size_t)(kk0 + key) * QKVN + 4096 + kvh * HD + scol,        \
                  &Kl[buf][c * 8]);                                                 \
    }                                                                               \
    _Pragma("unroll") for (int it = 0; it < 4; it++) {                              \
      int c = it * 256 + tid;                                                       \
      int d = c >> 3, slot = c & 7;                                                 \
      int scol = ((slot * 16) ^ ((d & 7) << 4)) >> 1;                               \
      gload_lds16(vt + (size_t)(kvh * HD + d) * S_LEN + kk0 + scol,                 \
                  &Vl[buf][c * 8]);                                                 \
    }                                                                               \
  } while (0)

  STAGE(0, 0);
  __syncthreads();

  for (int kt = 0; kt < nkt; kt++) {
    const int cur = kt & 1;
    if (kt + 1 < nkt) STAGE(cur ^ 1, kt + 1);  // in flight during compute

    if (kt <= kdiag) {
      const char* Kb = (const char*)&Kl[cur][0];
      const char* Vb = (const char*)&Vl[cur][0];
      const int k0 = kt * 64;
      // ---- QK^T: S^T[key][q], two 32-key blocks ----
      f32x16 sacc[2];
#pragma unroll
      for (int b = 0; b < 2; b++)
#pragma unroll
        for (int r = 0; r < 16; r++) sacc[b][r] = 0.f;
      __builtin_amdgcn_s_setprio(1);
#pragma unroll
      for (int dk = 0; dk < 8; dk++) {
        const int sA = ((2 * dk + h) ^ (l31 & 15)) * 16;
        bf16x8 kf0 = *(const bf16x8*)(Kb + l31 * 256 + sA);
        bf16x8 kf1 = *(const bf16x8*)(Kb + (32 + l31) * 256 + sA);
        sacc[0] = mfma32(kf0, qf[dk], sacc[0]);
        sacc[1] = mfma32(kf1, qf[dk], sacc[1]);
      }
      __builtin_amdgcn_s_setprio(0);
      // ---- softmax (lane-local; q = lane&31) ----
      float p[32];
#pragma unroll
      for (int b = 0; b < 2; b++)
#pragma unroll
        for (int r = 0; r < 16; r++) p[b * 16 + r] = sacc[b][r];
      if (kt == kdiag) {  // mask only on the diagonal tile
#pragma unroll
        for (int b = 0; b < 2; b++)
#pragma unroll
          for (int r = 0; r < 16; r++) {
            int keyg = k0 + b * 32 + (r & 3) + 8 * (r >> 2) + 4 * h;
            if (keyg > qg) p[b * 16 + r] = -INFINITY;
          }
      }
      // pairwise max tree (depth 5)
      float t16[16], t8[8], t4[4];
#pragma unroll
      for (int i = 0; i < 16; i++) t16[i] = fmaxf(p[2 * i], p[2 * i + 1]);
#pragma unroll
      for (int i = 0; i < 8; i++) t8[i] = fmaxf(t16[2 * i], t16[2 * i + 1]);
#pragma unroll
      for (int i = 0; i < 4; i++) t4[i] = fmaxf(t8[2 * i], t8[2 * i + 1]);
      float pm = fmaxf(fmaxf(t4[0], t4[1]), fmaxf(t4[2], t4[3]));
      pm = fmaxf(pm, __shfl_xor(pm, 32));
      if (__any(pm - m > 8.f)) {  // defer-max (T13)
        float mn = fmaxf(m, pm);
        float corr = __expf(m - mn);
        m = mn;
        lsum *= corr;
#pragma unroll
        for (int dt = 0; dt < 4; dt++)
#pragma unroll
          for (int r = 0; r < 16; r++) acc[dt][r] *= corr;
      }
      float psum = 0.f;
#pragma unroll
      for (int i = 0; i < 32; i++) { p[i] = __expf(p[i] - m); psum += p[i]; }
      lsum += psum;
      // ---- PV: O^T += V^T * P, P-frags built in-register ----
      // permlane32_swap(W0,W2): W0 -> {lo:W0@h0, hi:W2@h0}, W2 -> {lo:W0@h1, hi:W2@h1}.
#pragma unroll
      for (int ks2 = 0; ks2 < 4; ks2++) {
        const int o8 = (ks2 >> 1) * 16 + (ks2 & 1) * 8;
        u32 W0 = pk_bf16(p[o8 + 0], p[o8 + 1]);
        u32 W1 = pk_bf16(p[o8 + 2], p[o8 + 3]);
        u32 W2 = pk_bf16(p[o8 + 4], p[o8 + 5]);
        u32 W3 = pk_bf16(p[o8 + 6], p[o8 + 7]);
        asm("v_permlane32_swap_b32 %0, %1" : "+v"(W0), "+v"(W2));
        asm("v_permlane32_swap_b32 %0, %1" : "+v"(W1), "+v"(W3));
        union { u32 wd[4]; bf16x8 v; } pu;
        pu.wd[0] = W0; pu.wd[1] = W1; pu.wd[2] = W2; pu.wd[3] = W3;
        __builtin_amdgcn_s_setprio(1);
#pragma unroll
        for (int dt = 0; dt < 4; dt++) {
          const int dr = dt * 32 + l31;
          const int sV = ((2 * ks2 + h) ^ (dr & 7)) * 16;
          bf16x8 vf = *(const bf16x8*)(Vb + dr * 128 + sV);
          acc[dt] = mfma32(vf, pu.v, acc[dt]);
        }
        __builtin_amdgcn_s_setprio(0);
      }
    }
    __syncthreads();  // drains vmcnt: next tile landed; buffers safe to swap
  }
#undef STAGE

  // ---- finalize: combine the two key-halves, normalize, store ----
  lsum += __shfl_xor(lsum, 32);
  const float inv = 1.f / lsum;
  __bf16* orow = o + (size_t)qg * OD + head * HD;
#pragma unroll
  for (int dt = 0; dt < 4; dt++)
#pragma unroll
    for (int rq = 0; rq < 4; rq++) {  // reg quads -> 4 consecutive d
      int d = dt * 32 + 8 * rq + 4 * h;
      bf16x4 ov = {(__bf16)(acc[dt][rq * 4 + 0] * inv), (__bf16)(acc[dt][rq * 4 + 1] * inv),
                   (__bf16)(acc[dt][rq * 4 + 2] * inv), (__bf16)(acc[dt][rq * 4 + 3] * inv)};
      *(bf16x4*)(orow + d) = ov;
    }
}

extern "C" void kernel_launch(void* const* d_in, const int* in_sizes, int n_in,
                              void* d_out, int out_size, void* d_ws, size_t ws_size,
                              hipStream_t stream) {
  const float* x  = (const float*)d_in[0];
  // d_in[1] = mask (tril causal; hard-coded in kernel)
  const float* wq = (const float*)d_in[2];
  const float* bq = (const float*)d_in[3];
  const float* wk = (const float*)d_in[4];
  const float* bk = (const float*)d_in[5];
  const float* wv = (const float*)d_in[6];
  const float* bv = (const float*)d_in[7];
  const float* wo = (const float*)d_in[8];
  const float* bo = (const float*)d_in[9];
  float* out = (float*)d_out;

  const size_t MB = 1024 * 1024;
  char* ws = (char*)d_ws;
  __bf16* xb    = (__bf16*)(ws);             //  8 MiB: 2048x2048 (dead after QKV GEMM)
  __bf16* wqkvT = (__bf16*)(ws + 8 * MB);    // 24 MiB (dead after QKV GEMM)
  __bf16* woT   = (__bf16*)(ws + 32 * MB);   // 16 MiB: 2048x4096
  __bf16* qkvb  = (__bf16*)(ws + 48 * MB);   // 24 MiB: 2048x6144
  __bf16* vtb   = (__bf16*)(ws + 72 * MB);   //  4 MiB: 8x128x2048
  __bf16* ob    = (__bf16*)(ws + 76 * MB);   // 16 MiB: 2048x4096
  float*  bqkv  = (float*)(ws + 92 * MB);    // 24 KiB
  float*  Cpart = (float*)(ws);              // 32 MiB: 2x(2048x2048 f32), reuses xb+wqkvT

  k_cvt<<<4096, 256, 0, stream>>>(x, xb, HIDDEN * S_LEN);
  k_transpose_cvt<<<dim3(128, 64), 256, 0, stream>>>(wq, wqkvT, HIDDEN, 4096);
  k_transpose_cvt<<<dim3(32, 64), 256, 0, stream>>>(wk, wqkvT + (size_t)4096 * HIDDEN, HIDDEN, 1024);
  k_transpose_cvt<<<dim3(32, 64), 256, 0, stream>>>(wv, wqkvT + (size_t)5120 * HIDDEN, HIDDEN, 1024);
  k_transpose_cvt<<<dim3(64, 128), 256, 0, stream>>>(wo, woT, 4096, HIDDEN);
  k_bias_concat<<<24, 256, 0, stream>>>(bq, bk, bv, bqkv);

  // QKV projection: 128x192 2-phase GEMM (512 blocks = 2/CU, full coverage)
  k_gemm8<<<512, 256, 0, stream>>>(xb, wqkvT, bqkv, qkvb, S_LEN, QKVN, HIDDEN,
                                   0.08838834764831845f, 4096);
  k_vtrans<<<dim3(S_LEN / 32, HD / 32, NKV), 256, 0, stream>>>(qkvb, vtb);
  k_attn<<<512, 256, 0, stream>>>(qkvb, vtb, ob);
  // O-projection: split-K=2, 2-phase counted-vmcnt dbuf (512 blocks = 2/CU)
  k_gemm_part<<<512, 256, 0, stream>>>(ob, woT, Cpart, S_LEN, HIDDEN, OD, OD / 2);
  k_ocombine<<<(S_LEN * HIDDEN) / 1024, 256, 0, stream>>>(
      Cpart, Cpart + (size_t)S_LEN * HIDDEN, bo, out);
}